// Round 5
// baseline (433.051 us; speedup 1.0000x reference)
//
#include <hip/hip_runtime.h>
#include <hip/hip_bf16.h>
#include <math.h>

// ---------------- problem constants ----------------
#define BROWS      16384
#define LN_EPS_F   1e-5f
#define MINW       0.001f
#define MINH       0.001f
#define MIND       0.001f
// float(np.log(np.exp(0.999) - 1.0))
#define EDGE_CONST_F 0.5397423505783211f

typedef __bf16 bf16x8 __attribute__((ext_vector_type(8)));
typedef float  f32x4  __attribute__((ext_vector_type(4)));

// fp32 -> bf16 RNE, and back, via bit ops
__device__ __forceinline__ ushort f2bf(float x) {
    union { float f; unsigned u; } v; v.f = x;
    unsigned u = v.u;
    u += 0x7fffu + ((u >> 16) & 1u);
    return (ushort)(u >> 16);
}
__device__ __forceinline__ float bf2f(ushort h) {
    union { unsigned u; float f; } v; v.u = ((unsigned)h) << 16;
    return v.f;
}

// ==================================================================
// MFMA GEMM, split-precision bf16x3, PHASE-SPLIT schedule (T3+T4+T5):
// 3 phases per K-step, one per bf16x3 pass (HH / HL / LH), each phase
// interleaving {stage next-tile loads || ds_read this pass's fragments
// || 16 MFMA} with barriers keeping waves role-split. Counted
// vmcnt(3) once per K-tile: next-tile loads never drained in-loop.
//  - P1 pre-read barrier publishes tile t (after my vmcnt(3)).
//  - every phase ends lgkmcnt(0) -> barrier, so buffer reads are
//    complete before any wave stages over that buffer (2 iters later).
// ==================================================================
__global__ __launch_bounds__(256, 2)
void gemm_bf16x3(const ushort* __restrict__ Ah, const ushort* __restrict__ Al,
                 const ushort* __restrict__ Bh, const ushort* __restrict__ Bl,
                 const float* __restrict__ bias,
                 float* __restrict__ C, int ldc, int Nstore, int Kpad)
{
    __shared__ ushort lds[32768];   // 64 KB: two [Ah|Al|Bh|Bl] tile buffers
    const int tid  = threadIdx.x;
    const int wid  = tid >> 6;
    const int lane = tid & 63;
    const int bm0  = blockIdx.x * 128;
    const int bn0  = blockIdx.y * 128;
    const int wm   = wid >> 1;
    const int wn   = wid & 1;
    const int l15  = lane & 15;
    const int kg   = lane >> 4;

    // staging source addresses (k-sliced pre-permuted global, m173 pattern)
    const ushort* gsrc[8];
    {
        const ushort* pb[4] = {Ah, Al, Bh, Bl};
        #pragma unroll
        for (int i = 0; i < 8; ++i) {
            const int F     = i * 4096 + tid * 16;
            const int pl    = F >> 13;
            const int chunk = (F & 8191) >> 4;
            const int kgrp  = chunk >> 7;
            const int row   = chunk & 127;
            const int r0    = (pl < 2) ? bm0 : bn0;
            gsrc[i] = pb[pl] + (size_t)(r0 + row) * Kpad + kgrp * 8;
        }
    }
    #define STAGE_ONE(i, bufbase, kelem)                                       \
        __builtin_amdgcn_global_load_lds(                                      \
            (const __attribute__((address_space(1))) void*)(gsrc[i] + (kelem)),\
            (__attribute__((address_space(3))) void*)(&lds[(bufbase) + (i) * 2048 + wid * 512]), \
            16, 0, 0)

    f32x4 acc[4][4];
    #pragma unroll
    for (int m = 0; m < 4; ++m)
        #pragma unroll
        for (int n = 0; n < 4; ++n)
            acc[m][n] = (f32x4){0.f, 0.f, 0.f, 0.f};

    const int aoff = kg * 1024 + (wm * 64 + l15) * 8;           // Ah plane
    const int boff = 8192 + kg * 1024 + (wn * 64 + l15) * 8;    // Bh plane
    const int nt = Kpad >> 5;

    // prologue: tile 0 fully staged into buf0
    STAGE_ONE(0, 0, 0); STAGE_ONE(1, 0, 0); STAGE_ONE(2, 0, 0); STAGE_ONE(3, 0, 0);
    STAGE_ONE(4, 0, 0); STAGE_ONE(5, 0, 0); STAGE_ONE(6, 0, 0); STAGE_ONE(7, 0, 0);
    int cur = 0;

    for (int t = 0; t < nt; ++t) {
        const int nxt = cur ^ 1;
        const int nb  = nxt * 16384;
        const int cb  = cur * 16384;
        const int ke  = (t + 1) * 32;
        const bool pf = (t + 1 < nt);

        // ---------------- phase 1: HH ----------------
        if (pf) { STAGE_ONE(0, nb, ke); STAGE_ONE(1, nb, ke); STAGE_ONE(2, nb, ke); }
        if (pf) { asm volatile("s_waitcnt vmcnt(3)" ::: "memory"); }
        else    { asm volatile("s_waitcnt vmcnt(0)" ::: "memory"); }
        __builtin_amdgcn_sched_barrier(0);
        __builtin_amdgcn_s_barrier();           // tile t visible to all waves
        asm volatile("" ::: "memory");

        bf16x8 aH[4], aL[4], bH[4], bL[4];
        #pragma unroll
        for (int m = 0; m < 4; ++m) aH[m] = *(const bf16x8*)&lds[cb + aoff + m * 128];
        #pragma unroll
        for (int n = 0; n < 4; ++n) bH[n] = *(const bf16x8*)&lds[cb + boff + n * 128];
        asm volatile("s_waitcnt lgkmcnt(0)" ::: "memory");
        __builtin_amdgcn_sched_barrier(0);
        __builtin_amdgcn_s_setprio(1);
        #pragma unroll
        for (int m = 0; m < 4; ++m)
            #pragma unroll
            for (int n = 0; n < 4; ++n)
                acc[m][n] = __builtin_amdgcn_mfma_f32_16x16x32_bf16(aH[m], bH[n], acc[m][n], 0, 0, 0);
        __builtin_amdgcn_s_setprio(0);
        __builtin_amdgcn_s_barrier();
        asm volatile("" ::: "memory");

        // ---------------- phase 2: HL ----------------
        if (pf) { STAGE_ONE(3, nb, ke); STAGE_ONE(4, nb, ke); STAGE_ONE(5, nb, ke); }
        #pragma unroll
        for (int n = 0; n < 4; ++n) bL[n] = *(const bf16x8*)&lds[cb + 4096 + boff + n * 128];
        asm volatile("s_waitcnt lgkmcnt(0)" ::: "memory");
        __builtin_amdgcn_sched_barrier(0);
        __builtin_amdgcn_s_setprio(1);
        #pragma unroll
        for (int m = 0; m < 4; ++m)
            #pragma unroll
            for (int n = 0; n < 4; ++n)
                acc[m][n] = __builtin_amdgcn_mfma_f32_16x16x32_bf16(aH[m], bL[n], acc[m][n], 0, 0, 0);
        __builtin_amdgcn_s_setprio(0);
        __builtin_amdgcn_s_barrier();
        asm volatile("" ::: "memory");

        // ---------------- phase 3: LH ----------------
        if (pf) { STAGE_ONE(6, nb, ke); STAGE_ONE(7, nb, ke); }
        #pragma unroll
        for (int m = 0; m < 4; ++m) aL[m] = *(const bf16x8*)&lds[cb + 4096 + aoff + m * 128];
        asm volatile("s_waitcnt lgkmcnt(0)" ::: "memory");
        __builtin_amdgcn_sched_barrier(0);
        __builtin_amdgcn_s_setprio(1);
        #pragma unroll
        for (int m = 0; m < 4; ++m)
            #pragma unroll
            for (int n = 0; n < 4; ++n)
                acc[m][n] = __builtin_amdgcn_mfma_f32_16x16x32_bf16(aL[m], bH[n], acc[m][n], 0, 0, 0);
        __builtin_amdgcn_s_setprio(0);
        __builtin_amdgcn_s_barrier();           // reads done (lgkm=0 above):
        asm volatile("" ::: "memory");          // buf[cur] safe to overwrite next iter
        cur = nxt;
    }
    #undef STAGE_ONE

    // epilogue: C/D mapping col = lane&15, row = (lane>>4)*4 + reg  [m89/m91]
    #pragma unroll
    for (int n = 0; n < 4; ++n) {
        const int col = bn0 + wn * 64 + n * 16 + l15;
        if (col < Nstore) {
            const float bs = bias[col];
            #pragma unroll
            for (int m = 0; m < 4; ++m) {
                const int row = bm0 + wm * 64 + m * 16 + kg * 4;
                #pragma unroll
                for (int r = 0; r < 4; ++r)
                    C[(size_t)(row + r) * ldc + col] = acc[m][n][r] + bs;
            }
        }
    }
}

// ==================================================================
// LayerNorm + ReLU, emitting hi/lo bf16 planes (+ actions, + zero pad)
// ==================================================================
__global__ __launch_bounds__(256)
void ln_relu_split(const float* __restrict__ Y,
                   const float* __restrict__ g, const float* __restrict__ b,
                   ushort* __restrict__ Xh, ushort* __restrict__ Xl, int xstride,
                   const float* __restrict__ actions, int dopad)
{
    __shared__ float red[4];
    const int row = blockIdx.x;
    const int tid = threadIdx.x;
    const float* y = Y + (size_t)row * 1024;

    const float4 v = *(const float4*)(y + tid * 4);
    float s = v.x + v.y + v.z + v.w;
    #pragma unroll
    for (int off = 32; off > 0; off >>= 1) s += __shfl_down(s, off, 64);
    if ((tid & 63) == 0) red[tid >> 6] = s;
    __syncthreads();
    const float mu = (red[0] + red[1] + red[2] + red[3]) * (1.f / 1024.f);
    __syncthreads();
    const float d0 = v.x - mu, d1 = v.y - mu, d2 = v.z - mu, d3 = v.w - mu;
    float s2 = d0 * d0 + d1 * d1 + d2 * d2 + d3 * d3;
    #pragma unroll
    for (int off = 32; off > 0; off >>= 1) s2 += __shfl_down(s2, off, 64);
    if ((tid & 63) == 0) red[tid >> 6] = s2;
    __syncthreads();
    const float var = (red[0] + red[1] + red[2] + red[3]) * (1.f / 1024.f);
    const float inv = 1.0f / sqrtf(var + LN_EPS_F);

    float o0 = fmaxf(0.f, d0 * inv * g[tid * 4 + 0] + b[tid * 4 + 0]);
    float o1 = fmaxf(0.f, d1 * inv * g[tid * 4 + 1] + b[tid * 4 + 1]);
    float o2 = fmaxf(0.f, d2 * inv * g[tid * 4 + 2] + b[tid * 4 + 2]);
    float o3 = fmaxf(0.f, d3 * inv * g[tid * 4 + 3] + b[tid * 4 + 3]);

    ushort4 oh, ol;
    oh.x = f2bf(o0); ol.x = f2bf(o0 - bf2f(oh.x));
    oh.y = f2bf(o1); ol.y = f2bf(o1 - bf2f(oh.y));
    oh.z = f2bf(o2); ol.z = f2bf(o2 - bf2f(oh.z));
    oh.w = f2bf(o3); ol.w = f2bf(o3 - bf2f(oh.w));
    *(ushort4*)(Xh + (size_t)row * xstride + tid * 4) = oh;
    *(ushort4*)(Xl + (size_t)row * xstride + tid * 4) = ol;

    if (actions != nullptr && tid < 16) {
        const float a = actions[(size_t)row * 16 + tid];
        const ushort h = f2bf(a);
        Xh[(size_t)row * xstride + 1024 + tid] = h;
        Xl[(size_t)row * xstride + 1024 + tid] = f2bf(a - bf2f(h));
    }
    if (dopad && tid >= 16 && tid < 64) {   // zero cols 1040..1087
        Xh[(size_t)row * xstride + 1024 + tid] = 0;
        Xl[(size_t)row * xstride + 1024 + tid] = 0;
    }
}

// ---------------- fp32 matrix -> hi/lo bf16 planes, 4 elems/thread ----------
__global__ __launch_bounds__(256)
void split_mat(const float* __restrict__ src, int scols,
               ushort* __restrict__ Dh, ushort* __restrict__ Dl,
               int dcols, int total)
{
    const int idx = (blockIdx.x * 256 + threadIdx.x) * 4;
    if (idx >= total) return;
    const int r = idx / dcols, c = idx % dcols;
    float e[4];
    if (c + 3 < scols) {
        const float4 v = *(const float4*)(src + (size_t)r * scols + c);
        e[0] = v.x; e[1] = v.y; e[2] = v.z; e[3] = v.w;
    } else {
        #pragma unroll
        for (int j = 0; j < 4; ++j)
            e[j] = (c + j < scols) ? src[(size_t)r * scols + c + j] : 0.f;
    }
    ushort4 h, l;
    h.x = f2bf(e[0]); l.x = f2bf(e[0] - bf2f(h.x));
    h.y = f2bf(e[1]); l.y = f2bf(e[1] - bf2f(h.y));
    h.z = f2bf(e[2]); l.z = f2bf(e[2] - bf2f(h.z));
    h.w = f2bf(e[3]); l.w = f2bf(e[3] - bf2f(h.w));
    *(ushort4*)(Dh + idx) = h;
    *(ushort4*)(Dl + idx) = l;
}

// ---------------- concatenated head weight [wv; wa; wb; 0pad] -> planes -----
__global__ __launch_bounds__(256)
void build_wcat_split(const float* __restrict__ wv, const float* __restrict__ wa,
                      const float* __restrict__ wb, const float* __restrict__ bv,
                      const float* __restrict__ ba, const float* __restrict__ bb,
                      ushort* __restrict__ Wh, ushort* __restrict__ Wl,
                      float* __restrict__ bcat)
{
    const int idx = blockIdx.x * 256 + threadIdx.x;
    if (idx < 512 * 1024) {
        const int n = idx >> 10, k = idx & 1023;
        const float v = (n < 383) ? wv[n * 1024 + k]
                       : (n == 383) ? wa[k]
                       : (n == 384) ? wb[k] : 0.f;
        const ushort h = f2bf(v);
        Wh[idx] = h;
        Wl[idx] = f2bf(v - bf2f(h));
    }
    if (idx < 512) {
        bcat[idx] = (idx < 383) ? bv[idx] : (idx == 383) ? ba[0]
                   : (idx == 384) ? bb[0] : 0.f;
    }
}

// ==================================================================
// spline: one WAVE per row (4 rows / 256-thr block)
// ==================================================================
__device__ __forceinline__ float softplus_f(float x) {
    return (x > 20.f) ? x : log1pf(expf(x));
}

__global__ __launch_bounds__(256)
void spline_rq(const float* __restrict__ P, float* __restrict__ Out)
{
    __shared__ float cw[4][132];
    __shared__ float ch[4][132];
    __shared__ float Dv[4][132];
    const int wid  = threadIdx.x >> 6;
    const int lane = threadIdx.x & 63;
    const int r    = blockIdx.x * 4 + wid;
    const float* p = P + (size_t)r * 385;
    const int e0 = 2 * lane, e1 = 2 * lane + 1;

    const float sa = expf(p[383]);
    const float sb = p[384];

    // ---- W: softmax + affine + pair-scan -> cw[0..128] ----
    const float w0 = p[e0], w1 = p[e1];
    float mx = fmaxf(w0, w1);
    #pragma unroll
    for (int off = 1; off < 64; off <<= 1) mx = fmaxf(mx, __shfl_xor(mx, off, 64));
    const float xw0 = expf(w0 - mx), xw1 = expf(w1 - mx);
    float sw = xw0 + xw1;
    #pragma unroll
    for (int off = 1; off < 64; off <<= 1) sw += __shfl_xor(sw, off, 64);
    const float cwn = (1.f - MINW * 128.f) / sw;
    const float Wv0 = MINW + cwn * xw0;
    const float Wv1 = MINW + cwn * xw1;
    float s = Wv0 + Wv1;
    #pragma unroll
    for (int off = 1; off < 64; off <<= 1) {
        const float t = __shfl_up(s, off, 64);
        if (lane >= off) s += t;
    }
    if (lane == 0) cw[wid][0] = 0.f;
    cw[wid][e1]     = s - Wv1;
    cw[wid][e1 + 1] = (lane == 63) ? 1.0f : s;

    // ---- H: softmax + affine + pair-scan -> ch[0..128] (scaled) ----
    const float h0 = p[128 + e0], h1 = p[128 + e1];
    float mh = fmaxf(h0, h1);
    #pragma unroll
    for (int off = 1; off < 64; off <<= 1) mh = fmaxf(mh, __shfl_xor(mh, off, 64));
    const float xh0 = expf(h0 - mh), xh1 = expf(h1 - mh);
    float sh = xh0 + xh1;
    #pragma unroll
    for (int off = 1; off < 64; off <<= 1) sh += __shfl_xor(sh, off, 64);
    const float chn = (1.f - MINH * 128.f) / sh;
    const float Hv0 = MINH + chn * xh0;
    const float Hv1 = MINH + chn * xh1;
    float t2 = Hv0 + Hv1;
    #pragma unroll
    for (int off = 1; off < 64; off <<= 1) {
        const float t = __shfl_up(t2, off, 64);
        if (lane >= off) t2 += t;
    }
    if (lane == 0) ch[wid][0] = sb;
    ch[wid][e1]     = sa * (t2 - Hv1) + sb;
    ch[wid][e1 + 1] = sa * t2 + sb;

    // ---- derivatives D[0..128] ----
    if (lane == 0) { Dv[wid][0] = EDGE_CONST_F; Dv[wid][128] = EDGE_CONST_F; }
    Dv[wid][e0 + 1] = MIND + softplus_f(p[256 + e0]);
    if (lane < 63) Dv[wid][e1 + 1] = MIND + softplus_f(p[256 + e1]);

    __syncthreads();

    // ---- evaluate 2 taus per lane ----
    #pragma unroll
    for (int t = 0; t < 2; ++t) {
        const int e = 2 * lane + t;
        const float tau = ((float)e + 0.5f) * (1.f / 128.f);
        int lo = 0, hi = 128;
        #pragma unroll
        for (int it = 0; it < 7; ++it) {
            const int mid = (lo + hi) >> 1;
            if (cw[wid][mid] <= tau) lo = mid; else hi = mid;
        }
        const int bin = lo;
        const float icw = cw[wid][bin];
        const float ibw = cw[wid][bin + 1] - icw;
        const float ich = ch[wid][bin];
        const float ih  = ch[wid][bin + 1] - ich;
        const float idelta = ih / ibw;
        const float dd0 = Dv[wid][bin];
        const float dd1 = Dv[wid][bin + 1];
        const float theta = (tau - icw) / ibw;
        const float tom = theta * (1.f - theta);
        const float num = ih * (idelta * theta * theta + dd0 * tom);
        const float den = idelta + (dd0 + dd1 - 2.f * idelta) * tom;
        Out[(size_t)r * 128 + e] = ich + num / den;
    }
}

// ==================================================================
extern "C" void kernel_launch(void* const* d_in, const int* in_sizes, int n_in,
                              void* d_out, int out_size, void* d_ws, size_t ws_size,
                              hipStream_t stream) {
    const float* inputs  = (const float*)d_in[0];
    const float* actions = (const float*)d_in[1];
    const float* w1      = (const float*)d_in[2];
    const float* b1      = (const float*)d_in[3];
    const float* ln1_g   = (const float*)d_in[4];
    const float* ln1_b   = (const float*)d_in[5];
    const float* w2      = (const float*)d_in[6];
    const float* b2      = (const float*)d_in[7];
    const float* ln2_g   = (const float*)d_in[8];
    const float* ln2_b   = (const float*)d_in[9];
    const float* wv      = (const float*)d_in[10];
    const float* bv      = (const float*)d_in[11];
    const float* wa      = (const float*)d_in[12];
    const float* ba      = (const float*)d_in[13];
    const float* wb      = (const float*)d_in[14];
    const float* bb      = (const float*)d_in[15];

    // ---- workspace layout ----
    float*  ws_y  = (float*)d_ws;                              // [16384][1024] f32
    ushort* ws_Xh = (ushort*)(ws_y + (size_t)16384 * 1024);    // [16384][1088] bf16 hi
    ushort* ws_Xl = ws_Xh + (size_t)16384 * 1088;              // lo plane
    ushort* w1h   = ws_Xl + (size_t)16384 * 1088;
    ushort* w1l   = w1h + 1024 * 256;
    ushort* w2h   = w1l + 1024 * 256;
    ushort* w2l   = w2h + 1024 * 1088;
    ushort* wch   = w2l + 1024 * 1088;
    ushort* wcl   = wch + 512 * 1024;
    float*  bcat  = (float*)(wcl + 512 * 1024);

    // ---- weight / input conversion to hi/lo planes ----
    split_mat<<<(16384 * 256 / 4 + 255) / 256, 256, 0, stream>>>(inputs, 256, ws_Xh, ws_Xl, 256, 16384 * 256);
    split_mat<<<(1024 * 256 / 4 + 255) / 256, 256, 0, stream>>>(w1, 256, w1h, w1l, 256, 1024 * 256);
    split_mat<<<(1024 * 1088 / 4 + 255) / 256, 256, 0, stream>>>(w2, 1040, w2h, w2l, 1088, 1024 * 1088);
    build_wcat_split<<<(512 * 1024 + 255) / 256, 256, 0, stream>>>(wv, wa, wb, bv, ba, bb, wch, wcl, bcat);

    // ---- layer 1 ----
    gemm_bf16x3<<<dim3(128, 8), 256, 0, stream>>>(ws_Xh, ws_Xl, w1h, w1l, b1, ws_y, 1024, 1024, 256);
    ln_relu_split<<<16384, 256, 0, stream>>>(ws_y, ln1_g, ln1_b, ws_Xh, ws_Xl, 1088, actions, 1);

    // ---- layer 2 (K padded 1040 -> 1088 with zeros) ----
    gemm_bf16x3<<<dim3(128, 8), 256, 0, stream>>>(ws_Xh, ws_Xl, w2h, w2l, b2, ws_y, 1024, 1024, 1088);
    ln_relu_split<<<16384, 256, 0, stream>>>(ws_y, ln2_g, ln2_b, ws_Xh, ws_Xl, 1024, nullptr, 0);

    // ---- head GEMM (N=512 padded, store 385 cols) -> params in ws_y ----
    gemm_bf16x3<<<dim3(128, 4), 256, 0, stream>>>(ws_Xh, ws_Xl, wch, wcl, bcat, ws_y, 385, 385, 1024);

    // ---- spline ----
    spline_rq<<<4096, 256, 0, stream>>>(ws_y, (float*)d_out);
}

// Round 6
// 421.402 us; speedup vs baseline: 1.0276x; 1.0276x over previous
//
#include <hip/hip_runtime.h>
#include <hip/hip_bf16.h>
#include <math.h>

// ---------------- problem constants ----------------
#define BROWS      16384
#define LN_EPS_F   1e-5f
#define MINW       0.001f
#define MINH       0.001f
#define MIND       0.001f
// float(np.log(np.exp(0.999) - 1.0))
#define EDGE_CONST_F 0.5397423505783211f

typedef __bf16 bf16x8 __attribute__((ext_vector_type(8)));
typedef float  f32x4  __attribute__((ext_vector_type(4)));

__device__ __forceinline__ ushort f2bf(float x) {
    union { float f; unsigned u; } v; v.f = x;
    unsigned u = v.u;
    u += 0x7fffu + ((u >> 16) & 1u);
    return (ushort)(u >> 16);
}
__device__ __forceinline__ float bf2f(ushort h) {
    union { unsigned u; float f; } v; v.u = ((unsigned)h) << 16;
    return v.f;
}

#define WAITV(n) do { asm volatile("s_waitcnt vmcnt(" #n ")" ::: "memory"); \
                      __builtin_amdgcn_sched_barrier(0); } while (0)
#define BARF()   do { __builtin_amdgcn_s_barrier(); \
                      asm volatile("" ::: "memory"); } while (0)

// ==================================================================
// m201-style 256-wide 8-wave deep-pipelined GEMM, bf16x3 split.
//   C = A @ B^T + bias. A planes [M][Kpad] hi/lo bf16, B planes [N][Kpad].
//   BM = MREP*32 (256 or 128), BN = 256, BK = 32. 8 waves (2m x 4n),
//   per-wave output (MREP*16) x 64. 3 phases per K-tile (HH/HL/LH).
//   K-tile = 4 pieces {Ah,Bh,Bl,Al}; piece staged 1 tile ahead, each
//   phase stages the piece-pair whose LDS region was read one full
//   tile earlier; counted vmcnt publishes exactly the piece the NEXT
//   phase reads (queue never drains). k-sliced LDS layout [kg][row][8]
//   (bank-conflict-free, verified r2-r5: SQ_LDS_BANK_CONFLICT = 0).
// ==================================================================
template<int MREP>
__global__ __launch_bounds__(512, 2)
void gemm_bf16x3_8p(const ushort* __restrict__ Ah, const ushort* __restrict__ Al,
                    const ushort* __restrict__ Bh, const ushort* __restrict__ Bl,
                    const float* __restrict__ bias,
                    float* __restrict__ C, int ldc, int Nstore, int Kpad)
{
    constexpr int BM   = MREP * 32;
    constexpr int LA   = MREP / 4;            // loads per A piece (2 or 1)
    constexpr int AH0  = 0;
    constexpr int AL0  = BM * 32;
    constexpr int BH0  = 2 * BM * 32;
    constexpr int BL0  = 2 * BM * 32 + 8192;
    constexpr int SBUF = 2 * BM * 32 + 16384; // elems per buffer

    __shared__ ushort lds[2 * SBUF];

    const int tid  = threadIdx.x;
    const int wid  = tid >> 6;        // 0..7
    const int lane = tid & 63;
    const int wm   = wid >> 2;        // 0..1
    const int wn   = wid & 3;         // 0..3
    const int l15  = lane & 15;
    const int kg   = lane >> 4;       // 0..3
    const int bm0  = blockIdx.x * BM;
    const int bn0  = blockIdx.y * 256;

    // staging source pointers: piece 0=Ah 1=Al 2=Bh 3=Bl, load i
    const ushort* sP[4][2];
    #pragma unroll
    for (int i = 0; i < 2; ++i) {
        if (i < LA) {
            const int c    = i * 512 + tid;
            const int kgrp = c / BM;
            const int row  = c % BM;
            const size_t off = (size_t)(bm0 + row) * Kpad + kgrp * 8;
            sP[0][i] = Ah + off;
            sP[1][i] = Al + off;
        }
        {
            const int c    = i * 512 + tid;
            const int kgrp = c >> 8;
            const int row  = c & 255;
            const size_t off = (size_t)(bn0 + row) * Kpad + kgrp * 8;
            sP[2][i] = Bh + off;
            sP[3][i] = Bl + off;
        }
    }
    // stage one piece (cnt loads) into buffer base bb at k-elem ke
    auto STAGE = [&](int pi, int dbase, int cnt, int bb, int ke) {
        #pragma unroll
        for (int i = 0; i < 2; ++i)
            if (i < cnt)
                __builtin_amdgcn_global_load_lds(
                    (const __attribute__((address_space(1))) void*)(sP[pi][i] + ke),
                    (__attribute__((address_space(3))) void*)(&lds[bb + dbase + i * 4096 + wid * 512]),
                    16, 0, 0);
    };

    f32x4 acc[MREP][4];
    #pragma unroll
    for (int m = 0; m < MREP; ++m)
        #pragma unroll
        for (int n = 0; n < 4; ++n)
            acc[m][n] = (f32x4){0.f, 0.f, 0.f, 0.f};

    const int arow = (wm * (BM / 2) + l15) * 8;   // + m*128 per frag
    const int brow = (wn * 64 + l15) * 8;         // + n*128 per frag
    const int nt = Kpad >> 5;

    // prologue: tile 0, piece order AhBh, Bl, Al (matches in-loop order)
    STAGE(0, AH0, LA, 0, 0); STAGE(2, BH0, 2, 0, 0);
    STAGE(3, BL0, 2, 0, 0);  STAGE(1, AL0, LA, 0, 0);
    if constexpr (MREP == 8) WAITV(4); else WAITV(3);   // AhBh(0) resident
    BARF();

    for (int t = 0; t < nt; ++t) {
        const int cb = (t & 1) * SBUF;
        const int nb = ((t + 1) & 1) * SBUF;
        const int ke = (t + 1) * 32;
        const bool pf = (t + 1 < nt);

        // ---------- P1: HH ----------
        bf16x8 aH[MREP], bH[4], bL[4], aL[MREP];
        #pragma unroll
        for (int m = 0; m < MREP; ++m)
            aH[m] = *(const bf16x8*)&lds[cb + AH0 + kg * (BM * 8) + arow + m * 128];
        #pragma unroll
        for (int n = 0; n < 4; ++n)
            bH[n] = *(const bf16x8*)&lds[cb + BH0 + kg * 2048 + brow + n * 128];
        if (pf) { STAGE(0, AH0, LA, nb, ke); STAGE(2, BH0, 2, nb, ke); }
        __builtin_amdgcn_s_setprio(1);
        #pragma unroll
        for (int m = 0; m < MREP; ++m)
            #pragma unroll
            for (int n = 0; n < 4; ++n)
                acc[m][n] = __builtin_amdgcn_mfma_f32_16x16x32_bf16(aH[m], bH[n], acc[m][n], 0, 0, 0);
        __builtin_amdgcn_s_setprio(0);
        if (pf) { if constexpr (MREP == 8) WAITV(6); else WAITV(4); }   // Bl(t) resident
        else    { if constexpr (MREP == 8) WAITV(2); else WAITV(1); }
        BARF();

        // ---------- P2: HL ----------
        #pragma unroll
        for (int n = 0; n < 4; ++n)
            bL[n] = *(const bf16x8*)&lds[cb + BL0 + kg * 2048 + brow + n * 128];
        if (pf) STAGE(3, BL0, 2, nb, ke);
        __builtin_amdgcn_s_setprio(1);
        #pragma unroll
        for (int m = 0; m < MREP; ++m)
            #pragma unroll
            for (int n = 0; n < 4; ++n)
                acc[m][n] = __builtin_amdgcn_mfma_f32_16x16x32_bf16(aH[m], bL[n], acc[m][n], 0, 0, 0);
        __builtin_amdgcn_s_setprio(0);
        if (pf) { if constexpr (MREP == 8) WAITV(6); else WAITV(5); }   // Al(t) resident
        else    WAITV(0);
        BARF();

        // ---------- P3: LH ----------
        #pragma unroll
        for (int m = 0; m < MREP; ++m)
            aL[m] = *(const bf16x8*)&lds[cb + AL0 + kg * (BM * 8) + arow + m * 128];
        if (pf) STAGE(1, AL0, LA, nb, ke);
        __builtin_amdgcn_s_setprio(1);
        #pragma unroll
        for (int m = 0; m < MREP; ++m)
            #pragma unroll
            for (int n = 0; n < 4; ++n)
                acc[m][n] = __builtin_amdgcn_mfma_f32_16x16x32_bf16(aL[m], bH[n], acc[m][n], 0, 0, 0);
        __builtin_amdgcn_s_setprio(0);
        if (pf) { if constexpr (MREP == 8) WAITV(4); else WAITV(3); }   // AhBh(t+1) resident
        BARF();
    }

    // epilogue: C/D mapping col = lane&15, row = (lane>>4)*4 + reg  [m89/m91]
    #pragma unroll
    for (int n = 0; n < 4; ++n) {
        const int col = bn0 + wn * 64 + n * 16 + l15;
        if (col < Nstore) {
            const float bs = bias[col];
            #pragma unroll
            for (int m = 0; m < MREP; ++m) {
                const int row = bm0 + wm * (BM / 2) + m * 16 + kg * 4;
                #pragma unroll
                for (int r = 0; r < 4; ++r)
                    C[(size_t)(row + r) * ldc + col] = acc[m][n][r] + bs;
            }
        }
    }
}

// ==================================================================
// LayerNorm + ReLU, emitting hi/lo bf16 planes (+ actions, + zero pad)
// ==================================================================
__global__ __launch_bounds__(256)
void ln_relu_split(const float* __restrict__ Y,
                   const float* __restrict__ g, const float* __restrict__ b,
                   ushort* __restrict__ Xh, ushort* __restrict__ Xl, int xstride,
                   const float* __restrict__ actions, int dopad)
{
    __shared__ float red[4];
    const int row = blockIdx.x;
    const int tid = threadIdx.x;
    const float* y = Y + (size_t)row * 1024;

    const float4 v = *(const float4*)(y + tid * 4);
    float s = v.x + v.y + v.z + v.w;
    #pragma unroll
    for (int off = 32; off > 0; off >>= 1) s += __shfl_down(s, off, 64);
    if ((tid & 63) == 0) red[tid >> 6] = s;
    __syncthreads();
    const float mu = (red[0] + red[1] + red[2] + red[3]) * (1.f / 1024.f);
    __syncthreads();
    const float d0 = v.x - mu, d1 = v.y - mu, d2 = v.z - mu, d3 = v.w - mu;
    float s2 = d0 * d0 + d1 * d1 + d2 * d2 + d3 * d3;
    #pragma unroll
    for (int off = 32; off > 0; off >>= 1) s2 += __shfl_down(s2, off, 64);
    if ((tid & 63) == 0) red[tid >> 6] = s2;
    __syncthreads();
    const float var = (red[0] + red[1] + red[2] + red[3]) * (1.f / 1024.f);
    const float inv = 1.0f / sqrtf(var + LN_EPS_F);

    float o0 = fmaxf(0.f, d0 * inv * g[tid * 4 + 0] + b[tid * 4 + 0]);
    float o1 = fmaxf(0.f, d1 * inv * g[tid * 4 + 1] + b[tid * 4 + 1]);
    float o2 = fmaxf(0.f, d2 * inv * g[tid * 4 + 2] + b[tid * 4 + 2]);
    float o3 = fmaxf(0.f, d3 * inv * g[tid * 4 + 3] + b[tid * 4 + 3]);

    ushort4 oh, ol;
    oh.x = f2bf(o0); ol.x = f2bf(o0 - bf2f(oh.x));
    oh.y = f2bf(o1); ol.y = f2bf(o1 - bf2f(oh.y));
    oh.z = f2bf(o2); ol.z = f2bf(o2 - bf2f(oh.z));
    oh.w = f2bf(o3); ol.w = f2bf(o3 - bf2f(oh.w));
    *(ushort4*)(Xh + (size_t)row * xstride + tid * 4) = oh;
    *(ushort4*)(Xl + (size_t)row * xstride + tid * 4) = ol;

    if (actions != nullptr && tid < 16) {
        const float a = actions[(size_t)row * 16 + tid];
        const ushort h = f2bf(a);
        Xh[(size_t)row * xstride + 1024 + tid] = h;
        Xl[(size_t)row * xstride + 1024 + tid] = f2bf(a - bf2f(h));
    }
    if (dopad && tid >= 16 && tid < 64) {   // zero cols 1040..1087
        Xh[(size_t)row * xstride + 1024 + tid] = 0;
        Xl[(size_t)row * xstride + 1024 + tid] = 0;
    }
}

// ---------------- fp32 matrix -> hi/lo bf16 planes, 4 elems/thread ----------
__global__ __launch_bounds__(256)
void split_mat(const float* __restrict__ src, int scols,
               ushort* __restrict__ Dh, ushort* __restrict__ Dl,
               int dcols, int total)
{
    const int idx = (blockIdx.x * 256 + threadIdx.x) * 4;
    if (idx >= total) return;
    const int r = idx / dcols, c = idx % dcols;
    float e[4];
    if (c + 3 < scols) {
        const float4 v = *(const float4*)(src + (size_t)r * scols + c);
        e[0] = v.x; e[1] = v.y; e[2] = v.z; e[3] = v.w;
    } else {
        #pragma unroll
        for (int j = 0; j < 4; ++j)
            e[j] = (c + j < scols) ? src[(size_t)r * scols + c + j] : 0.f;
    }
    ushort4 h, l;
    h.x = f2bf(e[0]); l.x = f2bf(e[0] - bf2f(h.x));
    h.y = f2bf(e[1]); l.y = f2bf(e[1] - bf2f(h.y));
    h.z = f2bf(e[2]); l.z = f2bf(e[2] - bf2f(h.z));
    h.w = f2bf(e[3]); l.w = f2bf(e[3] - bf2f(h.w));
    *(ushort4*)(Dh + idx) = h;
    *(ushort4*)(Dl + idx) = l;
}

// ---------------- concatenated head weight [wv; wa; wb; 0pad] -> planes -----
__global__ __launch_bounds__(256)
void build_wcat_split(const float* __restrict__ wv, const float* __restrict__ wa,
                      const float* __restrict__ wb, const float* __restrict__ bv,
                      const float* __restrict__ ba, const float* __restrict__ bb,
                      ushort* __restrict__ Wh, ushort* __restrict__ Wl,
                      float* __restrict__ bcat)
{
    const int idx = blockIdx.x * 256 + threadIdx.x;
    if (idx < 512 * 1024) {
        const int n = idx >> 10, k = idx & 1023;
        const float v = (n < 383) ? wv[n * 1024 + k]
                       : (n == 383) ? wa[k]
                       : (n == 384) ? wb[k] : 0.f;
        const ushort h = f2bf(v);
        Wh[idx] = h;
        Wl[idx] = f2bf(v - bf2f(h));
    }
    if (idx < 512) {
        bcat[idx] = (idx < 383) ? bv[idx] : (idx == 383) ? ba[0]
                   : (idx == 384) ? bb[0] : 0.f;
    }
}

// ==================================================================
// spline: one WAVE per row (4 rows / 256-thr block)
// ==================================================================
__device__ __forceinline__ float softplus_f(float x) {
    return (x > 20.f) ? x : log1pf(expf(x));
}

__global__ __launch_bounds__(256)
void spline_rq(const float* __restrict__ P, float* __restrict__ Out)
{
    __shared__ float cw[4][132];
    __shared__ float ch[4][132];
    __shared__ float Dv[4][132];
    const int wid  = threadIdx.x >> 6;
    const int lane = threadIdx.x & 63;
    const int r    = blockIdx.x * 4 + wid;
    const float* p = P + (size_t)r * 385;
    const int e0 = 2 * lane, e1 = 2 * lane + 1;

    const float sa = expf(p[383]);
    const float sb = p[384];

    // ---- W: softmax + affine + pair-scan -> cw[0..128] ----
    const float w0 = p[e0], w1 = p[e1];
    float mx = fmaxf(w0, w1);
    #pragma unroll
    for (int off = 1; off < 64; off <<= 1) mx = fmaxf(mx, __shfl_xor(mx, off, 64));
    const float xw0 = expf(w0 - mx), xw1 = expf(w1 - mx);
    float sw = xw0 + xw1;
    #pragma unroll
    for (int off = 1; off < 64; off <<= 1) sw += __shfl_xor(sw, off, 64);
    const float cwn = (1.f - MINW * 128.f) / sw;
    const float Wv0 = MINW + cwn * xw0;
    const float Wv1 = MINW + cwn * xw1;
    float s = Wv0 + Wv1;
    #pragma unroll
    for (int off = 1; off < 64; off <<= 1) {
        const float t = __shfl_up(s, off, 64);
        if (lane >= off) s += t;
    }
    if (lane == 0) cw[wid][0] = 0.f;
    cw[wid][e1]     = s - Wv1;
    cw[wid][e1 + 1] = (lane == 63) ? 1.0f : s;

    // ---- H: softmax + affine + pair-scan -> ch[0..128] (scaled) ----
    const float h0 = p[128 + e0], h1 = p[128 + e1];
    float mh = fmaxf(h0, h1);
    #pragma unroll
    for (int off = 1; off < 64; off <<= 1) mh = fmaxf(mh, __shfl_xor(mh, off, 64));
    const float xh0 = expf(h0 - mh), xh1 = expf(h1 - mh);
    float sh = xh0 + xh1;
    #pragma unroll
    for (int off = 1; off < 64; off <<= 1) sh += __shfl_xor(sh, off, 64);
    const float chn = (1.f - MINH * 128.f) / sh;
    const float Hv0 = MINH + chn * xh0;
    const float Hv1 = MINH + chn * xh1;
    float t2 = Hv0 + Hv1;
    #pragma unroll
    for (int off = 1; off < 64; off <<= 1) {
        const float t = __shfl_up(t2, off, 64);
        if (lane >= off) t2 += t;
    }
    if (lane == 0) ch[wid][0] = sb;
    ch[wid][e1]     = sa * (t2 - Hv1) + sb;
    ch[wid][e1 + 1] = sa * t2 + sb;

    // ---- derivatives D[0..128] ----
    if (lane == 0) { Dv[wid][0] = EDGE_CONST_F; Dv[wid][128] = EDGE_CONST_F; }
    Dv[wid][e0 + 1] = MIND + softplus_f(p[256 + e0]);
    if (lane < 63) Dv[wid][e1 + 1] = MIND + softplus_f(p[256 + e1]);

    __syncthreads();

    // ---- evaluate 2 taus per lane ----
    #pragma unroll
    for (int t = 0; t < 2; ++t) {
        const int e = 2 * lane + t;
        const float tau = ((float)e + 0.5f) * (1.f / 128.f);
        int lo = 0, hi = 128;
        #pragma unroll
        for (int it = 0; it < 7; ++it) {
            const int mid = (lo + hi) >> 1;
            if (cw[wid][mid] <= tau) lo = mid; else hi = mid;
        }
        const int bin = lo;
        const float icw = cw[wid][bin];
        const float ibw = cw[wid][bin + 1] - icw;
        const float ich = ch[wid][bin];
        const float ih  = ch[wid][bin + 1] - ich;
        const float idelta = ih / ibw;
        const float dd0 = Dv[wid][bin];
        const float dd1 = Dv[wid][bin + 1];
        const float theta = (tau - icw) / ibw;
        const float tom = theta * (1.f - theta);
        const float num = ih * (idelta * theta * theta + dd0 * tom);
        const float den = idelta + (dd0 + dd1 - 2.f * idelta) * tom;
        Out[(size_t)r * 128 + e] = ich + num / den;
    }
}

// ==================================================================
extern "C" void kernel_launch(void* const* d_in, const int* in_sizes, int n_in,
                              void* d_out, int out_size, void* d_ws, size_t ws_size,
                              hipStream_t stream) {
    const float* inputs  = (const float*)d_in[0];
    const float* actions = (const float*)d_in[1];
    const float* w1      = (const float*)d_in[2];
    const float* b1      = (const float*)d_in[3];
    const float* ln1_g   = (const float*)d_in[4];
    const float* ln1_b   = (const float*)d_in[5];
    const float* w2      = (const float*)d_in[6];
    const float* b2      = (const float*)d_in[7];
    const float* ln2_g   = (const float*)d_in[8];
    const float* ln2_b   = (const float*)d_in[9];
    const float* wv      = (const float*)d_in[10];
    const float* bv      = (const float*)d_in[11];
    const float* wa      = (const float*)d_in[12];
    const float* ba      = (const float*)d_in[13];
    const float* wb      = (const float*)d_in[14];
    const float* bb      = (const float*)d_in[15];

    // ---- workspace layout ----
    float*  ws_y  = (float*)d_ws;                              // [16384][1024] f32
    ushort* ws_Xh = (ushort*)(ws_y + (size_t)16384 * 1024);    // [16384][1088] bf16 hi
    ushort* ws_Xl = ws_Xh + (size_t)16384 * 1088;              // lo plane
    ushort* w1h   = ws_Xl + (size_t)16384 * 1088;
    ushort* w1l   = w1h + 1024 * 256;
    ushort* w2h   = w1l + 1024 * 256;
    ushort* w2l   = w2h + 1024 * 1088;
    ushort* wch   = w2l + 1024 * 1088;
    ushort* wcl   = wch + 512 * 1024;
    float*  bcat  = (float*)(wcl + 512 * 1024);

    // ---- weight / input conversion to hi/lo planes ----
    split_mat<<<(16384 * 256 / 4 + 255) / 256, 256, 0, stream>>>(inputs, 256, ws_Xh, ws_Xl, 256, 16384 * 256);
    split_mat<<<(1024 * 256 / 4 + 255) / 256, 256, 0, stream>>>(w1, 256, w1h, w1l, 256, 1024 * 256);
    split_mat<<<(1024 * 1088 / 4 + 255) / 256, 256, 0, stream>>>(w2, 1040, w2h, w2l, 1088, 1024 * 1088);
    build_wcat_split<<<(512 * 1024 + 255) / 256, 256, 0, stream>>>(wv, wa, wb, bv, ba, bb, wch, wcl, bcat);

    // ---- layer 1:  [16384,256] @ [1024,256]^T ----
    gemm_bf16x3_8p<8><<<dim3(64, 4), 512, 0, stream>>>(ws_Xh, ws_Xl, w1h, w1l, b1, ws_y, 1024, 1024, 256);
    ln_relu_split<<<16384, 256, 0, stream>>>(ws_y, ln1_g, ln1_b, ws_Xh, ws_Xl, 1088, actions, 1);

    // ---- layer 2:  [16384,1088] @ [1024,1088]^T (K padded with zeros) ----
    gemm_bf16x3_8p<8><<<dim3(64, 4), 512, 0, stream>>>(ws_Xh, ws_Xl, w2h, w2l, b2, ws_y, 1024, 1024, 1088);
    ln_relu_split<<<16384, 256, 0, stream>>>(ws_y, ln2_g, ln2_b, ws_Xh, ws_Xl, 1024, nullptr, 0);

    // ---- head: [16384,1024] @ [512,1024]^T, store 385 cols (BM=128 variant) ----
    gemm_bf16x3_8p<4><<<dim3(128, 2), 512, 0, stream>>>(ws_Xh, ws_Xl, wch, wcl, bcat, ws_y, 385, 385, 1024);

    // ---- spline ----
    spline_rq<<<4096, 256, 0, stream>>>(ws_y, (float*)d_out);
}

// Round 7
// 387.884 us; speedup vs baseline: 1.1164x; 1.0864x over previous
//
#include <hip/hip_runtime.h>
#include <hip/hip_bf16.h>
#include <math.h>

// ---------------- problem constants ----------------
#define BROWS      16384
#define LN_EPS_F   1e-5f
#define MINW       0.001f
#define MINH       0.001f
#define MIND       0.001f
// float(np.log(np.exp(0.999) - 1.0))
#define EDGE_CONST_F 0.5397423505783211f

typedef __bf16 bf16x8 __attribute__((ext_vector_type(8)));
typedef float  f32x4  __attribute__((ext_vector_type(4)));

__device__ __forceinline__ ushort f2bf(float x) {
    union { float f; unsigned u; } v; v.f = x;
    unsigned u = v.u;
    u += 0x7fffu + ((u >> 16) & 1u);
    return (ushort)(u >> 16);
}
__device__ __forceinline__ float bf2f(ushort h) {
    union { unsigned u; float f; } v; v.u = ((unsigned)h) << 16;
    return v.f;
}

#define WAITV(n) do { asm volatile("s_waitcnt vmcnt(" #n ")" ::: "memory"); \
                      __builtin_amdgcn_sched_barrier(0); } while (0)
#define BARF()   do { __builtin_amdgcn_s_barrier(); \
                      asm volatile("" ::: "memory"); } while (0)

// ==================================================================
// 256-wide 8-wave deep-pipelined GEMM, bf16x3 split, COALESCED staging.
//   C = A @ B^T + bias. A planes [M][Kpad] hi/lo bf16, B planes [N][Kpad].
//   BM = MREP*32, BN = 256, BK = 32. 8 waves (2m x 4n). 3 phases per
//   K-tile (HH/HL/LH); pieces {Ah,Bh,Bl,Al} staged 1 tile ahead with
//   counted vmcnt (schedule identical to r6).
//
//   LDS piece layout (r7 change): row-major 16B chunks with XOR swizzle.
//     chunk(row,kg) at c = pr*8 + (((row&1)*4+kg) ^ (pr&7)), pr = row>>1.
//   - global_load_lds dest stays LINEAR (HW requirement, m104);
//   - SOURCE address is the inverse permutation -> each wave-load reads
//     16 consecutive rows x 64B contiguous = 16 full cache lines
//     (kills the r2-r6 row-gather: 64 x 16B-of-64B lines, 4x L2 ampl.);
//   - fragment reads apply the same XOR; per lane-octet slots are a
//     bijective perm of 0..7 -> conflict-free.
// ==================================================================
template<int MREP>
__global__ __launch_bounds__(512, 2)
void gemm_bf16x3_8p(const ushort* __restrict__ Ah, const ushort* __restrict__ Al,
                    const ushort* __restrict__ Bh, const ushort* __restrict__ Bl,
                    const float* __restrict__ bias,
                    float* __restrict__ C, int ldc, int Nstore, int Kpad)
{
    constexpr int BM   = MREP * 32;
    constexpr int LA   = MREP / 4;            // loads per A piece (2 or 1)
    constexpr int AH0  = 0;
    constexpr int AL0  = BM * 32;
    constexpr int BH0  = 2 * BM * 32;
    constexpr int BL0  = 2 * BM * 32 + 8192;
    constexpr int SBUF = 2 * BM * 32 + 16384; // elems per buffer

    __shared__ ushort lds[2 * SBUF];

    const int tid  = threadIdx.x;
    const int wid  = tid >> 6;        // 0..7
    const int lane = tid & 63;
    const int wm   = wid >> 2;        // 0..1
    const int wn   = wid & 3;         // 0..3
    const int l15  = lane & 15;
    const int kg   = lane >> 4;       // 0..3
    const int bm0  = blockIdx.x * BM;
    const int bn0  = blockIdx.y * 256;

    // ---- staging source pointers: inverse of the LDS swizzle ----
    // piece 0=Ah 1=Al 2=Bh 3=Bl, load i covers chunks [i*512, i*512+512)
    const ushort* sP[4][2];
    #pragma unroll
    for (int i = 0; i < 2; ++i) {
        if (i < LA) {                      // A pieces (R = BM rows)
            const int c   = i * 512 + tid;
            const int pr  = c >> 3;
            const int s   = (c & 7) ^ (pr & 7);
            const int row = pr * 2 + (s >> 2);
            const int kgv = s & 3;
            const size_t off = (size_t)(bm0 + row) * Kpad + kgv * 8;
            sP[0][i] = Ah + off;
            sP[1][i] = Al + off;
        }
        {                                  // B pieces (R = 256 rows)
            const int c   = i * 512 + tid;
            const int pr  = c >> 3;
            const int s   = (c & 7) ^ (pr & 7);
            const int row = pr * 2 + (s >> 2);
            const int kgv = s & 3;
            const size_t off = (size_t)(bn0 + row) * Kpad + kgv * 8;
            sP[2][i] = Bh + off;
            sP[3][i] = Bl + off;
        }
    }
    // stage one piece (cnt loads) into buffer base bb at k-elem ke
    auto STAGE = [&](int pi, int dbase, int cnt, int bb, int ke) {
        #pragma unroll
        for (int i = 0; i < 2; ++i)
            if (i < cnt)
                __builtin_amdgcn_global_load_lds(
                    (const __attribute__((address_space(1))) void*)(sP[pi][i] + ke),
                    (__attribute__((address_space(3))) void*)(&lds[bb + dbase + i * 4096 + wid * 512]),
                    16, 0, 0);
    };

    f32x4 acc[MREP][4];
    #pragma unroll
    for (int m = 0; m < MREP; ++m)
        #pragma unroll
        for (int n = 0; n < 4; ++n)
            acc[m][n] = (f32x4){0.f, 0.f, 0.f, 0.f};

    // ---- swizzled fragment read bases (ushort units, within piece) ----
    // row = base + m*16 + l15 ; pr = row>>1 ; slot = ((row&1)*4+kg)^(pr&7)
    // off = pr*64 + slot*8 ; per-m/n step = 8 pairs * 64 = 512
    const int slotA = (((lane & 1) * 4 + kg) ^ ((l15 >> 1) & 7)) * 8;
    const int aswz  = wm * (BM * 16) + (l15 >> 1) * 64 + slotA;
    const int bswz  = wn * 2048      + (l15 >> 1) * 64 + slotA;
    const int nt = Kpad >> 5;

    // prologue: tile 0, piece order AhBh, Bl, Al (matches in-loop order)
    STAGE(0, AH0, LA, 0, 0); STAGE(2, BH0, 2, 0, 0);
    STAGE(3, BL0, 2, 0, 0);  STAGE(1, AL0, LA, 0, 0);
    if constexpr (MREP == 8) WAITV(4); else WAITV(3);   // AhBh(0) resident
    BARF();

    for (int t = 0; t < nt; ++t) {
        const int cb = (t & 1) * SBUF;
        const int nb = ((t + 1) & 1) * SBUF;
        const int ke = (t + 1) * 32;
        const bool pf = (t + 1 < nt);

        // ---------- P1: HH ----------
        bf16x8 aH[MREP], bH[4], bL[4], aL[MREP];
        #pragma unroll
        for (int m = 0; m < MREP; ++m)
            aH[m] = *(const bf16x8*)&lds[cb + AH0 + aswz + m * 512];
        #pragma unroll
        for (int n = 0; n < 4; ++n)
            bH[n] = *(const bf16x8*)&lds[cb + BH0 + bswz + n * 512];
        if (pf) { STAGE(0, AH0, LA, nb, ke); STAGE(2, BH0, 2, nb, ke); }
        __builtin_amdgcn_s_setprio(1);
        #pragma unroll
        for (int m = 0; m < MREP; ++m)
            #pragma unroll
            for (int n = 0; n < 4; ++n)
                acc[m][n] = __builtin_amdgcn_mfma_f32_16x16x32_bf16(aH[m], bH[n], acc[m][n], 0, 0, 0);
        __builtin_amdgcn_s_setprio(0);
        if (pf) { if constexpr (MREP == 8) WAITV(6); else WAITV(4); }   // Bl(t) resident
        else    { if constexpr (MREP == 8) WAITV(2); else WAITV(1); }
        BARF();

        // ---------- P2: HL ----------
        #pragma unroll
        for (int n = 0; n < 4; ++n)
            bL[n] = *(const bf16x8*)&lds[cb + BL0 + bswz + n * 512];
        if (pf) STAGE(3, BL0, 2, nb, ke);
        __builtin_amdgcn_s_setprio(1);
        #pragma unroll
        for (int m = 0; m < MREP; ++m)
            #pragma unroll
            for (int n = 0; n < 4; ++n)
                acc[m][n] = __builtin_amdgcn_mfma_f32_16x16x32_bf16(aH[m], bL[n], acc[m][n], 0, 0, 0);
        __builtin_amdgcn_s_setprio(0);
        if (pf) { if constexpr (MREP == 8) WAITV(6); else WAITV(5); }   // Al(t) resident
        else    WAITV(0);
        BARF();

        // ---------- P3: LH ----------
        #pragma unroll
        for (int m = 0; m < MREP; ++m)
            aL[m] = *(const bf16x8*)&lds[cb + AL0 + aswz + m * 512];
        if (pf) STAGE(1, AL0, LA, nb, ke);
        __builtin_amdgcn_s_setprio(1);
        #pragma unroll
        for (int m = 0; m < MREP; ++m)
            #pragma unroll
            for (int n = 0; n < 4; ++n)
                acc[m][n] = __builtin_amdgcn_mfma_f32_16x16x32_bf16(aL[m], bH[n], acc[m][n], 0, 0, 0);
        __builtin_amdgcn_s_setprio(0);
        if (pf) { if constexpr (MREP == 8) WAITV(4); else WAITV(3); }   // AhBh(t+1) resident
        BARF();
    }

    // epilogue: C/D mapping col = lane&15, row = (lane>>4)*4 + reg  [m89/m91]
    #pragma unroll
    for (int n = 0; n < 4; ++n) {
        const int col = bn0 + wn * 64 + n * 16 + l15;
        if (col < Nstore) {
            const float bs = bias[col];
            #pragma unroll
            for (int m = 0; m < MREP; ++m) {
                const int row = bm0 + wm * (BM / 2) + m * 16 + kg * 4;
                #pragma unroll
                for (int r = 0; r < 4; ++r)
                    C[(size_t)(row + r) * ldc + col] = acc[m][n][r] + bs;
            }
        }
    }
}

// ==================================================================
// LayerNorm + ReLU, emitting hi/lo bf16 planes (+ actions, + zero pad)
// ==================================================================
__global__ __launch_bounds__(256)
void ln_relu_split(const float* __restrict__ Y,
                   const float* __restrict__ g, const float* __restrict__ b,
                   ushort* __restrict__ Xh, ushort* __restrict__ Xl, int xstride,
                   const float* __restrict__ actions, int dopad)
{
    __shared__ float red[4];
    const int row = blockIdx.x;
    const int tid = threadIdx.x;
    const float* y = Y + (size_t)row * 1024;

    const float4 v = *(const float4*)(y + tid * 4);
    float s = v.x + v.y + v.z + v.w;
    #pragma unroll
    for (int off = 32; off > 0; off >>= 1) s += __shfl_down(s, off, 64);
    if ((tid & 63) == 0) red[tid >> 6] = s;
    __syncthreads();
    const float mu = (red[0] + red[1] + red[2] + red[3]) * (1.f / 1024.f);
    __syncthreads();
    const float d0 = v.x - mu, d1 = v.y - mu, d2 = v.z - mu, d3 = v.w - mu;
    float s2 = d0 * d0 + d1 * d1 + d2 * d2 + d3 * d3;
    #pragma unroll
    for (int off = 32; off > 0; off >>= 1) s2 += __shfl_down(s2, off, 64);
    if ((tid & 63) == 0) red[tid >> 6] = s2;
    __syncthreads();
    const float var = (red[0] + red[1] + red[2] + red[3]) * (1.f / 1024.f);
    const float inv = 1.0f / sqrtf(var + LN_EPS_F);

    float o0 = fmaxf(0.f, d0 * inv * g[tid * 4 + 0] + b[tid * 4 + 0]);
    float o1 = fmaxf(0.f, d1 * inv * g[tid * 4 + 1] + b[tid * 4 + 1]);
    float o2 = fmaxf(0.f, d2 * inv * g[tid * 4 + 2] + b[tid * 4 + 2]);
    float o3 = fmaxf(0.f, d3 * inv * g[tid * 4 + 3] + b[tid * 4 + 3]);

    ushort4 oh, ol;
    oh.x = f2bf(o0); ol.x = f2bf(o0 - bf2f(oh.x));
    oh.y = f2bf(o1); ol.y = f2bf(o1 - bf2f(oh.y));
    oh.z = f2bf(o2); ol.z = f2bf(o2 - bf2f(oh.z));
    oh.w = f2bf(o3); ol.w = f2bf(o3 - bf2f(oh.w));
    *(ushort4*)(Xh + (size_t)row * xstride + tid * 4) = oh;
    *(ushort4*)(Xl + (size_t)row * xstride + tid * 4) = ol;

    if (actions != nullptr && tid < 16) {
        const float a = actions[(size_t)row * 16 + tid];
        const ushort h = f2bf(a);
        Xh[(size_t)row * xstride + 1024 + tid] = h;
        Xl[(size_t)row * xstride + 1024 + tid] = f2bf(a - bf2f(h));
    }
    if (dopad && tid >= 16 && tid < 64) {   // zero cols 1040..1087
        Xh[(size_t)row * xstride + 1024 + tid] = 0;
        Xl[(size_t)row * xstride + 1024 + tid] = 0;
    }
}

// ---------------- fp32 matrix -> hi/lo bf16 planes, 4 elems/thread ----------
__global__ __launch_bounds__(256)
void split_mat(const float* __restrict__ src, int scols,
               ushort* __restrict__ Dh, ushort* __restrict__ Dl,
               int dcols, int total)
{
    const int idx = (blockIdx.x * 256 + threadIdx.x) * 4;
    if (idx >= total) return;
    const int r = idx / dcols, c = idx % dcols;
    float e[4];
    if (c + 3 < scols) {
        const float4 v = *(const float4*)(src + (size_t)r * scols + c);
        e[0] = v.x; e[1] = v.y; e[2] = v.z; e[3] = v.w;
    } else {
        #pragma unroll
        for (int j = 0; j < 4; ++j)
            e[j] = (c + j < scols) ? src[(size_t)r * scols + c + j] : 0.f;
    }
    ushort4 h, l;
    h.x = f2bf(e[0]); l.x = f2bf(e[0] - bf2f(h.x));
    h.y = f2bf(e[1]); l.y = f2bf(e[1] - bf2f(h.y));
    h.z = f2bf(e[2]); l.z = f2bf(e[2] - bf2f(h.z));
    h.w = f2bf(e[3]); l.w = f2bf(e[3] - bf2f(h.w));
    *(ushort4*)(Dh + idx) = h;
    *(ushort4*)(Dl + idx) = l;
}

// ---------------- concatenated head weight [wv; wa; wb; 0pad] -> planes -----
__global__ __launch_bounds__(256)
void build_wcat_split(const float* __restrict__ wv, const float* __restrict__ wa,
                      const float* __restrict__ wb, const float* __restrict__ bv,
                      const float* __restrict__ ba, const float* __restrict__ bb,
                      ushort* __restrict__ Wh, ushort* __restrict__ Wl,
                      float* __restrict__ bcat)
{
    const int idx = blockIdx.x * 256 + threadIdx.x;
    if (idx < 512 * 1024) {
        const int n = idx >> 10, k = idx & 1023;
        const float v = (n < 383) ? wv[n * 1024 + k]
                       : (n == 383) ? wa[k]
                       : (n == 384) ? wb[k] : 0.f;
        const ushort h = f2bf(v);
        Wh[idx] = h;
        Wl[idx] = f2bf(v - bf2f(h));
    }
    if (idx < 512) {
        bcat[idx] = (idx < 383) ? bv[idx] : (idx == 383) ? ba[0]
                   : (idx == 384) ? bb[0] : 0.f;
    }
}

// ==================================================================
// spline: one WAVE per row (4 rows / 256-thr block)
// ==================================================================
__device__ __forceinline__ float softplus_f(float x) {
    return (x > 20.f) ? x : log1pf(expf(x));
}

__global__ __launch_bounds__(256)
void spline_rq(const float* __restrict__ P, float* __restrict__ Out)
{
    __shared__ float cw[4][132];
    __shared__ float ch[4][132];
    __shared__ float Dv[4][132];
    const int wid  = threadIdx.x >> 6;
    const int lane = threadIdx.x & 63;
    const int r    = blockIdx.x * 4 + wid;
    const float* p = P + (size_t)r * 385;
    const int e0 = 2 * lane, e1 = 2 * lane + 1;

    const float sa = expf(p[383]);
    const float sb = p[384];

    // ---- W: softmax + affine + pair-scan -> cw[0..128] ----
    const float w0 = p[e0], w1 = p[e1];
    float mx = fmaxf(w0, w1);
    #pragma unroll
    for (int off = 1; off < 64; off <<= 1) mx = fmaxf(mx, __shfl_xor(mx, off, 64));
    const float xw0 = expf(w0 - mx), xw1 = expf(w1 - mx);
    float sw = xw0 + xw1;
    #pragma unroll
    for (int off = 1; off < 64; off <<= 1) sw += __shfl_xor(sw, off, 64);
    const float cwn = (1.f - MINW * 128.f) / sw;
    const float Wv0 = MINW + cwn * xw0;
    const float Wv1 = MINW + cwn * xw1;
    float s = Wv0 + Wv1;
    #pragma unroll
    for (int off = 1; off < 64; off <<= 1) {
        const float t = __shfl_up(s, off, 64);
        if (lane >= off) s += t;
    }
    if (lane == 0) cw[wid][0] = 0.f;
    cw[wid][e1]     = s - Wv1;
    cw[wid][e1 + 1] = (lane == 63) ? 1.0f : s;

    // ---- H: softmax + affine + pair-scan -> ch[0..128] (scaled) ----
    const float h0 = p[128 + e0], h1 = p[128 + e1];
    float mh = fmaxf(h0, h1);
    #pragma unroll
    for (int off = 1; off < 64; off <<= 1) mh = fmaxf(mh, __shfl_xor(mh, off, 64));
    const float xh0 = expf(h0 - mh), xh1 = expf(h1 - mh);
    float sh = xh0 + xh1;
    #pragma unroll
    for (int off = 1; off < 64; off <<= 1) sh += __shfl_xor(sh, off, 64);
    const float chn = (1.f - MINH * 128.f) / sh;
    const float Hv0 = MINH + chn * xh0;
    const float Hv1 = MINH + chn * xh1;
    float t2 = Hv0 + Hv1;
    #pragma unroll
    for (int off = 1; off < 64; off <<= 1) {
        const float t = __shfl_up(t2, off, 64);
        if (lane >= off) t2 += t;
    }
    if (lane == 0) ch[wid][0] = sb;
    ch[wid][e1]     = sa * (t2 - Hv1) + sb;
    ch[wid][e1 + 1] = sa * t2 + sb;

    // ---- derivatives D[0..128] ----
    if (lane == 0) { Dv[wid][0] = EDGE_CONST_F; Dv[wid][128] = EDGE_CONST_F; }
    Dv[wid][e0 + 1] = MIND + softplus_f(p[256 + e0]);
    if (lane < 63) Dv[wid][e1 + 1] = MIND + softplus_f(p[256 + e1]);

    __syncthreads();

    // ---- evaluate 2 taus per lane ----
    #pragma unroll
    for (int t = 0; t < 2; ++t) {
        const int e = 2 * lane + t;
        const float tau = ((float)e + 0.5f) * (1.f / 128.f);
        int lo = 0, hi = 128;
        #pragma unroll
        for (int it = 0; it < 7; ++it) {
            const int mid = (lo + hi) >> 1;
            if (cw[wid][mid] <= tau) lo = mid; else hi = mid;
        }
        const int bin = lo;
        const float icw = cw[wid][bin];
        const float ibw = cw[wid][bin + 1] - icw;
        const float ich = ch[wid][bin];
        const float ih  = ch[wid][bin + 1] - ich;
        const float idelta = ih / ibw;
        const float dd0 = Dv[wid][bin];
        const float dd1 = Dv[wid][bin + 1];
        const float theta = (tau - icw) / ibw;
        const float tom = theta * (1.f - theta);
        const float num = ih * (idelta * theta * theta + dd0 * tom);
        const float den = idelta + (dd0 + dd1 - 2.f * idelta) * tom;
        Out[(size_t)r * 128 + e] = ich + num / den;
    }
}

// ==================================================================
extern "C" void kernel_launch(void* const* d_in, const int* in_sizes, int n_in,
                              void* d_out, int out_size, void* d_ws, size_t ws_size,
                              hipStream_t stream) {
    const float* inputs  = (const float*)d_in[0];
    const float* actions = (const float*)d_in[1];
    const float* w1      = (const float*)d_in[2];
    const float* b1      = (const float*)d_in[3];
    const float* ln1_g   = (const float*)d_in[4];
    const float* ln1_b   = (const float*)d_in[5];
    const float* w2      = (const float*)d_in[6];
    const float* b2      = (const float*)d_in[7];
    const float* ln2_g   = (const float*)d_in[8];
    const float* ln2_b   = (const float*)d_in[9];
    const float* wv      = (const float*)d_in[10];
    const float* bv      = (const float*)d_in[11];
    const float* wa      = (const float*)d_in[12];
    const float* ba      = (const float*)d_in[13];
    const float* wb      = (const float*)d_in[14];
    const float* bb      = (const float*)d_in[15];

    // ---- workspace layout ----
    float*  ws_y  = (float*)d_ws;                              // [16384][1024] f32
    ushort* ws_Xh = (ushort*)(ws_y + (size_t)16384 * 1024);    // [16384][1088] bf16 hi
    ushort* ws_Xl = ws_Xh + (size_t)16384 * 1088;              // lo plane
    ushort* w1h   = ws_Xl + (size_t)16384 * 1088;
    ushort* w1l   = w1h + 1024 * 256;
    ushort* w2h   = w1l + 1024 * 256;
    ushort* w2l   = w2h + 1024 * 1088;
    ushort* wch   = w2l + 1024 * 1088;
    ushort* wcl   = wch + 512 * 1024;
    float*  bcat  = (float*)(wcl + 512 * 1024);

    // ---- weight / input conversion to hi/lo planes ----
    split_mat<<<(16384 * 256 / 4 + 255) / 256, 256, 0, stream>>>(inputs, 256, ws_Xh, ws_Xl, 256, 16384 * 256);
    split_mat<<<(1024 * 256 / 4 + 255) / 256, 256, 0, stream>>>(w1, 256, w1h, w1l, 256, 1024 * 256);
    split_mat<<<(1024 * 1088 / 4 + 255) / 256, 256, 0, stream>>>(w2, 1040, w2h, w2l, 1088, 1024 * 1088);
    build_wcat_split<<<(512 * 1024 + 255) / 256, 256, 0, stream>>>(wv, wa, wb, bv, ba, bb, wch, wcl, bcat);

    // ---- layer 1:  [16384,256] @ [1024,256]^T ----
    gemm_bf16x3_8p<8><<<dim3(64, 4), 512, 0, stream>>>(ws_Xh, ws_Xl, w1h, w1l, b1, ws_y, 1024, 1024, 256);
    ln_relu_split<<<16384, 256, 0, stream>>>(ws_y, ln1_g, ln1_b, ws_Xh, ws_Xl, 1088, actions, 1);

    // ---- layer 2:  [16384,1088] @ [1024,1088]^T (K padded with zeros) ----
    gemm_bf16x3_8p<8><<<dim3(64, 4), 512, 0, stream>>>(ws_Xh, ws_Xl, w2h, w2l, b2, ws_y, 1024, 1024, 1088);
    ln_relu_split<<<16384, 256, 0, stream>>>(ws_y, ln2_g, ln2_b, ws_Xh, ws_Xl, 1024, nullptr, 0);

    // ---- head: [16384,1024] @ [512,1024]^T, store 385 cols (BM=128 variant) ----
    gemm_bf16x3_8p<4><<<dim3(128, 2), 512, 0, stream>>>(ws_Xh, ws_Xl, wch, wcl, bcat, ws_y, 385, 385, 1024);

    // ---- spline ----
    spline_rq<<<4096, 256, 0, stream>>>(ws_y, (float*)d_out);
}

// Round 8
// 387.774 us; speedup vs baseline: 1.1168x; 1.0003x over previous
//
#include <hip/hip_runtime.h>
#include <hip/hip_bf16.h>
#include <math.h>

// ---------------- problem constants ----------------
#define BROWS      16384
#define LN_EPS_F   1e-5f
#define MINW       0.001f
#define MINH       0.001f
#define MIND       0.001f
// float(np.log(np.exp(0.999) - 1.0))
#define EDGE_CONST_F 0.5397423505783211f

typedef __bf16 bf16x8 __attribute__((ext_vector_type(8)));
typedef float  f32x4  __attribute__((ext_vector_type(4)));

__device__ __forceinline__ ushort f2bf(float x) {
    union { float f; unsigned u; } v; v.f = x;
    unsigned u = v.u;
    u += 0x7fffu + ((u >> 16) & 1u);
    return (ushort)(u >> 16);
}
__device__ __forceinline__ float bf2f(ushort h) {
    union { unsigned u; float f; } v; v.u = ((unsigned)h) << 16;
    return v.f;
}

#define WAITV(n) do { asm volatile("s_waitcnt vmcnt(" #n ")" ::: "memory"); \
                      __builtin_amdgcn_sched_barrier(0); } while (0)
#define BARF()   do { __builtin_amdgcn_sched_barrier(0);                    \
                      __builtin_amdgcn_s_barrier();                         \
                      asm volatile("" ::: "memory"); } while (0)

// ==================================================================
// 256-wide 8-wave pipelined GEMM, bf16x3 split, ROTATED READ schedule.
//   Pass order per K-tile: HH(aH,bH) -> LH(aL,bH) -> HL(aH,bL).
//   Reads run one phase ahead of use so ds_read and MFMA overlap
//   within each wave (m201's core mechanism):
//     P3(t-1) pre-reads bH(t)  (bH regs dead after P2 -> free)
//     P1(t): STAGE AhBh(t+1) | read aH(t) | MFMA HH | WAITV(SAB) | BAR
//     P2(t): STAGE Bl(t+1)   | read aL(t) | MFMA LH            (no bar)
//     P3(t): WAITV(2) | BAR | read bL(t), bH(t+1) | STAGE Al(t+1) | MFMA HL
//   Only 2 barriers/tile. Hazards: every LDS read is consumed by an
//   MFMA issued before the wave's next barrier; each region's
//   overwrite is >=2 barriers after its last read (opposite buffer).
//   Coalesced staging + XOR-swizzled LDS layout from r7 (verified:
//   conflicts = 0). C/D mapping m89/m91 (verified r2-r7).
// ==================================================================
template<int MREP>
__global__ __launch_bounds__(512, 2)
void gemm_bf16x3_8p(const ushort* __restrict__ Ah, const ushort* __restrict__ Al,
                    const ushort* __restrict__ Bh, const ushort* __restrict__ Bl,
                    const float* __restrict__ bias,
                    float* __restrict__ C, int ldc, int Nstore, int Kpad)
{
    constexpr int BM   = MREP * 32;
    constexpr int LA   = MREP / 4;            // loads per A piece (2 or 1)
    constexpr int AH0  = 0;
    constexpr int AL0  = BM * 32;
    constexpr int BH0  = 2 * BM * 32;
    constexpr int BL0  = 2 * BM * 32 + 8192;
    constexpr int SBUF = 2 * BM * 32 + 16384; // elems per buffer

    __shared__ ushort lds[2 * SBUF];

    const int tid  = threadIdx.x;
    const int wid  = tid >> 6;        // 0..7
    const int lane = tid & 63;
    const int wm   = wid >> 2;        // 0..1
    const int wn   = wid & 3;         // 0..3
    const int l15  = lane & 15;
    const int kg   = lane >> 4;       // 0..3
    const int bm0  = blockIdx.x * BM;
    const int bn0  = blockIdx.y * 256;

    // ---- staging source pointers: inverse of the LDS XOR swizzle ----
    const ushort* sP[4][2];
    #pragma unroll
    for (int i = 0; i < 2; ++i) {
        if (i < LA) {                      // A pieces (BM rows)
            const int c   = i * 512 + tid;
            const int pr  = c >> 3;
            const int s   = (c & 7) ^ (pr & 7);
            const int row = pr * 2 + (s >> 2);
            const int kgv = s & 3;
            const size_t off = (size_t)(bm0 + row) * Kpad + kgv * 8;
            sP[0][i] = Ah + off;
            sP[1][i] = Al + off;
        }
        {                                  // B pieces (256 rows)
            const int c   = i * 512 + tid;
            const int pr  = c >> 3;
            const int s   = (c & 7) ^ (pr & 7);
            const int row = pr * 2 + (s >> 2);
            const int kgv = s & 3;
            const size_t off = (size_t)(bn0 + row) * Kpad + kgv * 8;
            sP[2][i] = Bh + off;
            sP[3][i] = Bl + off;
        }
    }
    auto STAGE = [&](int pi, int dbase, int cnt, int bb, int ke) {
        #pragma unroll
        for (int i = 0; i < 2; ++i)
            if (i < cnt)
                __builtin_amdgcn_global_load_lds(
                    (const __attribute__((address_space(1))) void*)(sP[pi][i] + ke),
                    (__attribute__((address_space(3))) void*)(&lds[bb + dbase + i * 4096 + wid * 512]),
                    16, 0, 0);
    };

    f32x4 acc[MREP][4];
    #pragma unroll
    for (int m = 0; m < MREP; ++m)
        #pragma unroll
        for (int n = 0; n < 4; ++n)
            acc[m][n] = (f32x4){0.f, 0.f, 0.f, 0.f};

    // swizzled fragment read bases (r7 layout, verified conflict-free)
    const int slotA = (((lane & 1) * 4 + kg) ^ ((l15 >> 1) & 7)) * 8;
    const int aswz  = wm * (BM * 16) + (l15 >> 1) * 64 + slotA;
    const int bswz  = wn * 2048      + (l15 >> 1) * 64 + slotA;
    const int nt = Kpad >> 5;

    // ---- prologue: stage tile 0, publish AhBh(0), pre-read bH(0) ----
    STAGE(0, AH0, LA, 0, 0); STAGE(2, BH0, 2, 0, 0);
    STAGE(3, BL0, 2, 0, 0);  STAGE(1, AL0, LA, 0, 0);
    if constexpr (MREP == 8) WAITV(4); else WAITV(3);   // AhBh(0) landed
    BARF();

    bf16x8 bH[4];
    #pragma unroll
    for (int n = 0; n < 4; ++n)
        bH[n] = *(const bf16x8*)&lds[BH0 + bswz + n * 512];

    for (int t = 0; t < nt; ++t) {
        const int cb = (t & 1) * SBUF;
        const int nb = ((t + 1) & 1) * SBUF;
        const int ke = (t + 1) * 32;
        const bool pf = (t + 1 < nt);

        // ---------- P1: HH (aH x bH); stage AhBh(t+1) ----------
        if (pf) { STAGE(0, AH0, LA, nb, ke); STAGE(2, BH0, 2, nb, ke); }
        bf16x8 aH[MREP], aL[MREP], bL[4];
        #pragma unroll
        for (int m = 0; m < MREP; ++m)
            aH[m] = *(const bf16x8*)&lds[cb + AH0 + aswz + m * 512];
        __builtin_amdgcn_s_setprio(1);
        #pragma unroll
        for (int m = 0; m < MREP; ++m)
            #pragma unroll
            for (int n = 0; n < 4; ++n)
                acc[m][n] = __builtin_amdgcn_mfma_f32_16x16x32_bf16(aH[m], bH[n], acc[m][n], 0, 0, 0);
        __builtin_amdgcn_s_setprio(0);
        if (pf) { if constexpr (MREP == 8) WAITV(4); else WAITV(3); }  // Bl(t),Al(t) landed
        else    WAITV(0);
        BARF();                                   // publish Bl(t), Al(t)

        // ---------- P2: LH (aL x bH); stage Bl(t+1); no barrier ----------
        if (pf) STAGE(3, BL0, 2, nb, ke);
        #pragma unroll
        for (int m = 0; m < MREP; ++m)
            aL[m] = *(const bf16x8*)&lds[cb + AL0 + aswz + m * 512];
        __builtin_amdgcn_s_setprio(1);
        #pragma unroll
        for (int m = 0; m < MREP; ++m)
            #pragma unroll
            for (int n = 0; n < 4; ++n)
                acc[m][n] = __builtin_amdgcn_mfma_f32_16x16x32_bf16(aL[m], bH[n], acc[m][n], 0, 0, 0);
        __builtin_amdgcn_s_setprio(0);

        // ---------- P3: HL (aH x bL); pre-read bH(t+1); stage Al(t+1) ----------
        if (pf) WAITV(2); else WAITV(0);          // AhBh(t+1) landed
        BARF();                                   // publish AhBh(t+1)
        #pragma unroll
        for (int n = 0; n < 4; ++n)
            bL[n] = *(const bf16x8*)&lds[cb + BL0 + bswz + n * 512];
        if (pf) {
            #pragma unroll
            for (int n = 0; n < 4; ++n)
                bH[n] = *(const bf16x8*)&lds[nb + BH0 + bswz + n * 512];
            STAGE(1, AL0, LA, nb, ke);
        }
        __builtin_amdgcn_s_setprio(1);
        #pragma unroll
        for (int m = 0; m < MREP; ++m)
            #pragma unroll
            for (int n = 0; n < 4; ++n)
                acc[m][n] = __builtin_amdgcn_mfma_f32_16x16x32_bf16(aH[m], bL[n], acc[m][n], 0, 0, 0);
        __builtin_amdgcn_s_setprio(0);
    }

    // epilogue: C/D mapping col = lane&15, row = (lane>>4)*4 + reg  [m89/m91]
    #pragma unroll
    for (int n = 0; n < 4; ++n) {
        const int col = bn0 + wn * 64 + n * 16 + l15;
        if (col < Nstore) {
            const float bs = bias[col];
            #pragma unroll
            for (int m = 0; m < MREP; ++m) {
                const int row = bm0 + wm * (BM / 2) + m * 16 + kg * 4;
                #pragma unroll
                for (int r = 0; r < 4; ++r)
                    C[(size_t)(row + r) * ldc + col] = acc[m][n][r] + bs;
            }
        }
    }
}

// ==================================================================
// LayerNorm + ReLU, emitting hi/lo bf16 planes (+ actions, + zero pad)
// ==================================================================
__global__ __launch_bounds__(256)
void ln_relu_split(const float* __restrict__ Y,
                   const float* __restrict__ g, const float* __restrict__ b,
                   ushort* __restrict__ Xh, ushort* __restrict__ Xl, int xstride,
                   const float* __restrict__ actions, int dopad)
{
    __shared__ float red[4];
    const int row = blockIdx.x;
    const int tid = threadIdx.x;
    const float* y = Y + (size_t)row * 1024;

    const float4 v = *(const float4*)(y + tid * 4);
    float s = v.x + v.y + v.z + v.w;
    #pragma unroll
    for (int off = 32; off > 0; off >>= 1) s += __shfl_down(s, off, 64);
    if ((tid & 63) == 0) red[tid >> 6] = s;
    __syncthreads();
    const float mu = (red[0] + red[1] + red[2] + red[3]) * (1.f / 1024.f);
    __syncthreads();
    const float d0 = v.x - mu, d1 = v.y - mu, d2 = v.z - mu, d3 = v.w - mu;
    float s2 = d0 * d0 + d1 * d1 + d2 * d2 + d3 * d3;
    #pragma unroll
    for (int off = 32; off > 0; off >>= 1) s2 += __shfl_down(s2, off, 64);
    if ((tid & 63) == 0) red[tid >> 6] = s2;
    __syncthreads();
    const float var = (red[0] + red[1] + red[2] + red[3]) * (1.f / 1024.f);
    const float inv = 1.0f / sqrtf(var + LN_EPS_F);

    float o0 = fmaxf(0.f, d0 * inv * g[tid * 4 + 0] + b[tid * 4 + 0]);
    float o1 = fmaxf(0.f, d1 * inv * g[tid * 4 + 1] + b[tid * 4 + 1]);
    float o2 = fmaxf(0.f, d2 * inv * g[tid * 4 + 2] + b[tid * 4 + 2]);
    float o3 = fmaxf(0.f, d3 * inv * g[tid * 4 + 3] + b[tid * 4 + 3]);

    ushort4 oh, ol;
    oh.x = f2bf(o0); ol.x = f2bf(o0 - bf2f(oh.x));
    oh.y = f2bf(o1); ol.y = f2bf(o1 - bf2f(oh.y));
    oh.z = f2bf(o2); ol.z = f2bf(o2 - bf2f(oh.z));
    oh.w = f2bf(o3); ol.w = f2bf(o3 - bf2f(oh.w));
    *(ushort4*)(Xh + (size_t)row * xstride + tid * 4) = oh;
    *(ushort4*)(Xl + (size_t)row * xstride + tid * 4) = ol;

    if (actions != nullptr && tid < 16) {
        const float a = actions[(size_t)row * 16 + tid];
        const ushort h = f2bf(a);
        Xh[(size_t)row * xstride + 1024 + tid] = h;
        Xl[(size_t)row * xstride + 1024 + tid] = f2bf(a - bf2f(h));
    }
    if (dopad && tid >= 16 && tid < 32) {   // zero cols 1040..1055
        Xh[(size_t)row * xstride + 1024 + tid] = 0;
        Xl[(size_t)row * xstride + 1024 + tid] = 0;
    }
}

// ---------------- fp32 matrix -> hi/lo bf16 planes, 4 elems/thread ----------
__global__ __launch_bounds__(256)
void split_mat(const float* __restrict__ src, int scols,
               ushort* __restrict__ Dh, ushort* __restrict__ Dl,
               int dcols, int total)
{
    const int idx = (blockIdx.x * 256 + threadIdx.x) * 4;
    if (idx >= total) return;
    const int r = idx / dcols, c = idx % dcols;
    float e[4];
    if (c + 3 < scols) {
        const float4 v = *(const float4*)(src + (size_t)r * scols + c);
        e[0] = v.x; e[1] = v.y; e[2] = v.z; e[3] = v.w;
    } else {
        #pragma unroll
        for (int j = 0; j < 4; ++j)
            e[j] = (c + j < scols) ? src[(size_t)r * scols + c + j] : 0.f;
    }
    ushort4 h, l;
    h.x = f2bf(e[0]); l.x = f2bf(e[0] - bf2f(h.x));
    h.y = f2bf(e[1]); l.y = f2bf(e[1] - bf2f(h.y));
    h.z = f2bf(e[2]); l.z = f2bf(e[2] - bf2f(h.z));
    h.w = f2bf(e[3]); l.w = f2bf(e[3] - bf2f(h.w));
    *(ushort4*)(Dh + idx) = h;
    *(ushort4*)(Dl + idx) = l;
}

// ---------------- concatenated head weight [wv; wa; wb; 0pad] -> planes -----
__global__ __launch_bounds__(256)
void build_wcat_split(const float* __restrict__ wv, const float* __restrict__ wa,
                      const float* __restrict__ wb, const float* __restrict__ bv,
                      const float* __restrict__ ba, const float* __restrict__ bb,
                      ushort* __restrict__ Wh, ushort* __restrict__ Wl,
                      float* __restrict__ bcat)
{
    const int idx = blockIdx.x * 256 + threadIdx.x;
    if (idx < 512 * 1024) {
        const int n = idx >> 10, k = idx & 1023;
        const float v = (n < 383) ? wv[n * 1024 + k]
                       : (n == 383) ? wa[k]
                       : (n == 384) ? wb[k] : 0.f;
        const ushort h = f2bf(v);
        Wh[idx] = h;
        Wl[idx] = f2bf(v - bf2f(h));
    }
    if (idx < 512) {
        bcat[idx] = (idx < 383) ? bv[idx] : (idx == 383) ? ba[0]
                   : (idx == 384) ? bb[0] : 0.f;
    }
}

// ==================================================================
// spline: one WAVE per row (4 rows / 256-thr block)
// ==================================================================
__device__ __forceinline__ float softplus_f(float x) {
    return (x > 20.f) ? x : log1pf(expf(x));
}

__global__ __launch_bounds__(256)
void spline_rq(const float* __restrict__ P, float* __restrict__ Out)
{
    __shared__ float cw[4][132];
    __shared__ float ch[4][132];
    __shared__ float Dv[4][132];
    const int wid  = threadIdx.x >> 6;
    const int lane = threadIdx.x & 63;
    const int r    = blockIdx.x * 4 + wid;
    const float* p = P + (size_t)r * 385;
    const int e0 = 2 * lane, e1 = 2 * lane + 1;

    const float sa = expf(p[383]);
    const float sb = p[384];

    // ---- W: softmax + affine + pair-scan -> cw[0..128] ----
    const float w0 = p[e0], w1 = p[e1];
    float mx = fmaxf(w0, w1);
    #pragma unroll
    for (int off = 1; off < 64; off <<= 1) mx = fmaxf(mx, __shfl_xor(mx, off, 64));
    const float xw0 = expf(w0 - mx), xw1 = expf(w1 - mx);
    float sw = xw0 + xw1;
    #pragma unroll
    for (int off = 1; off < 64; off <<= 1) sw += __shfl_xor(sw, off, 64);
    const float cwn = (1.f - MINW * 128.f) / sw;
    const float Wv0 = MINW + cwn * xw0;
    const float Wv1 = MINW + cwn * xw1;
    float s = Wv0 + Wv1;
    #pragma unroll
    for (int off = 1; off < 64; off <<= 1) {
        const float t = __shfl_up(s, off, 64);
        if (lane >= off) s += t;
    }
    if (lane == 0) cw[wid][0] = 0.f;
    cw[wid][e1]     = s - Wv1;
    cw[wid][e1 + 1] = (lane == 63) ? 1.0f : s;

    // ---- H: softmax + affine + pair-scan -> ch[0..128] (scaled) ----
    const float h0 = p[128 + e0], h1 = p[128 + e1];
    float mh = fmaxf(h0, h1);
    #pragma unroll
    for (int off = 1; off < 64; off <<= 1) mh = fmaxf(mh, __shfl_xor(mh, off, 64));
    const float xh0 = expf(h0 - mh), xh1 = expf(h1 - mh);
    float sh = xh0 + xh1;
    #pragma unroll
    for (int off = 1; off < 64; off <<= 1) sh += __shfl_xor(sh, off, 64);
    const float chn = (1.f - MINH * 128.f) / sh;
    const float Hv0 = MINH + chn * xh0;
    const float Hv1 = MINH + chn * xh1;
    float t2 = Hv0 + Hv1;
    #pragma unroll
    for (int off = 1; off < 64; off <<= 1) {
        const float t = __shfl_up(t2, off, 64);
        if (lane >= off) t2 += t;
    }
    if (lane == 0) ch[wid][0] = sb;
    ch[wid][e1]     = sa * (t2 - Hv1) + sb;
    ch[wid][e1 + 1] = sa * t2 + sb;

    // ---- derivatives D[0..128] ----
    if (lane == 0) { Dv[wid][0] = EDGE_CONST_F; Dv[wid][128] = EDGE_CONST_F; }
    Dv[wid][e0 + 1] = MIND + softplus_f(p[256 + e0]);
    if (lane < 63) Dv[wid][e1 + 1] = MIND + softplus_f(p[256 + e1]);

    __syncthreads();

    // ---- evaluate 2 taus per lane ----
    #pragma unroll
    for (int t = 0; t < 2; ++t) {
        const int e = 2 * lane + t;
        const float tau = ((float)e + 0.5f) * (1.f / 128.f);
        int lo = 0, hi = 128;
        #pragma unroll
        for (int it = 0; it < 7; ++it) {
            const int mid = (lo + hi) >> 1;
            if (cw[wid][mid] <= tau) lo = mid; else hi = mid;
        }
        const int bin = lo;
        const float icw = cw[wid][bin];
        const float ibw = cw[wid][bin + 1] - icw;
        const float ich = ch[wid][bin];
        const float ih  = ch[wid][bin + 1] - ich;
        const float idelta = ih / ibw;
        const float dd0 = Dv[wid][bin];
        const float dd1 = Dv[wid][bin + 1];
        const float theta = (tau - icw) / ibw;
        const float tom = theta * (1.f - theta);
        const float num = ih * (idelta * theta * theta + dd0 * tom);
        const float den = idelta + (dd0 + dd1 - 2.f * idelta) * tom;
        Out[(size_t)r * 128 + e] = ich + num / den;
    }
}

// ==================================================================
extern "C" void kernel_launch(void* const* d_in, const int* in_sizes, int n_in,
                              void* d_out, int out_size, void* d_ws, size_t ws_size,
                              hipStream_t stream) {
    const float* inputs  = (const float*)d_in[0];
    const float* actions = (const float*)d_in[1];
    const float* w1      = (const float*)d_in[2];
    const float* b1      = (const float*)d_in[3];
    const float* ln1_g   = (const float*)d_in[4];
    const float* ln1_b   = (const float*)d_in[5];
    const float* w2      = (const float*)d_in[6];
    const float* b2      = (const float*)d_in[7];
    const float* ln2_g   = (const float*)d_in[8];
    const float* ln2_b   = (const float*)d_in[9];
    const float* wv      = (const float*)d_in[10];
    const float* bv      = (const float*)d_in[11];
    const float* wa      = (const float*)d_in[12];
    const float* ba      = (const float*)d_in[13];
    const float* wb      = (const float*)d_in[14];
    const float* bb      = (const float*)d_in[15];

    // ---- workspace layout (stride 1056 for layer-2 K) ----
    float*  ws_y  = (float*)d_ws;                              // [16384][1024] f32
    ushort* ws_Xh = (ushort*)(ws_y + (size_t)16384 * 1024);    // [16384][1056] bf16 hi
    ushort* ws_Xl = ws_Xh + (size_t)16384 * 1056;              // lo plane
    ushort* w1h   = ws_Xl + (size_t)16384 * 1056;
    ushort* w1l   = w1h + 1024 * 256;
    ushort* w2h   = w1l + 1024 * 256;
    ushort* w2l   = w2h + 1024 * 1056;
    ushort* wch   = w2l + 1024 * 1056;
    ushort* wcl   = wch + 512 * 1024;
    float*  bcat  = (float*)(wcl + 512 * 1024);

    // ---- weight / input conversion to hi/lo planes ----
    split_mat<<<(16384 * 256 / 4 + 255) / 256, 256, 0, stream>>>(inputs, 256, ws_Xh, ws_Xl, 256, 16384 * 256);
    split_mat<<<(1024 * 256 / 4 + 255) / 256, 256, 0, stream>>>(w1, 256, w1h, w1l, 256, 1024 * 256);
    split_mat<<<(1024 * 1056 / 4 + 255) / 256, 256, 0, stream>>>(w2, 1040, w2h, w2l, 1056, 1024 * 1056);
    build_wcat_split<<<(512 * 1024 + 255) / 256, 256, 0, stream>>>(wv, wa, wb, bv, ba, bb, wch, wcl, bcat);

    // ---- layer 1:  [16384,256] @ [1024,256]^T ----
    gemm_bf16x3_8p<8><<<dim3(64, 4), 512, 0, stream>>>(ws_Xh, ws_Xl, w1h, w1l, b1, ws_y, 1024, 1024, 256);
    ln_relu_split<<<16384, 256, 0, stream>>>(ws_y, ln1_g, ln1_b, ws_Xh, ws_Xl, 1056, actions, 1);

    // ---- layer 2:  [16384,1056] @ [1024,1056]^T (K padded with zeros) ----
    gemm_bf16x3_8p<8><<<dim3(64, 4), 512, 0, stream>>>(ws_Xh, ws_Xl, w2h, w2l, b2, ws_y, 1024, 1024, 1056);
    ln_relu_split<<<16384, 256, 0, stream>>>(ws_y, ln2_g, ln2_b, ws_Xh, ws_Xl, 1024, nullptr, 0);

    // ---- head: [16384,1024] @ [512,1024]^T, store 385 cols (BM=128 variant) ----
    gemm_bf16x3_8p<4><<<dim3(128, 2), 512, 0, stream>>>(ws_Xh, ws_Xl, wch, wcl, bcat, ws_y, 385, 385, 1024);

    // ---- spline ----
    spline_rq<<<4096, 256, 0, stream>>>(ws_y, (float*)d_out);
}

// Round 9
// 372.536 us; speedup vs baseline: 1.1624x; 1.0409x over previous
//
#include <hip/hip_runtime.h>
#include <hip/hip_bf16.h>
#include <math.h>

// ---------------- problem constants ----------------
#define BROWS      16384
#define LN_EPS_F   1e-5f
#define MINW       0.001f
#define MINH       0.001f
#define MIND       0.001f
// float(np.log(np.exp(0.999) - 1.0))
#define EDGE_CONST_F 0.5397423505783211f

typedef __bf16 bf16x8 __attribute__((ext_vector_type(8)));
typedef float  f32x4  __attribute__((ext_vector_type(4)));

__device__ __forceinline__ ushort f2bf(float x) {
    union { float f; unsigned u; } v; v.f = x;
    unsigned u = v.u;
    u += 0x7fffu + ((u >> 16) & 1u);
    return (ushort)(u >> 16);
}
__device__ __forceinline__ float bf2f(ushort h) {
    union { unsigned u; float f; } v; v.u = ((unsigned)h) << 16;
    return v.f;
}

// ==================================================================
// m97-structure GEMM, bf16x3 split: 128x128 tile, 4 waves, SINGLE
// 32KB LDS buffer, 2 syncthreads per K-tile, 3 blocks/CU co-resident
// (launch_bounds(256,3) caps VGPR at ~168). Latency hiding comes from
// CROSS-BLOCK overlap (m114/m97 mechanism), not in-block pipelining —
// r3-r8 established that in-block schedule levers are null at 1-2
// blocks/CU while nothing (MFMA/LDS/L2/HBM) is saturated.
//   LDS layout: 4 pieces {Ah,Al,Bh,Bl} x 8KB, XOR-swizzled 16B chunks
//   (r7 scheme, BM=128): chunk(row,kg) at pr*8 + (((row&1)*4+kg)^(pr&7)),
//   pr=row>>1. Staging source inverts the map -> fully coalesced
//   (16 consecutive rows x 64B per wave-load). Reads: 2-way bank
//   aliasing only (free, m136); measured 0 conflicts r7/r8.
// ==================================================================
template<int DUMMY>
__global__ __launch_bounds__(256, 3)
void gemm_bf16x3_sb(const ushort* __restrict__ Ah, const ushort* __restrict__ Al,
                    const ushort* __restrict__ Bh, const ushort* __restrict__ Bl,
                    const float* __restrict__ bias,
                    float* __restrict__ C, int ldc, int Nstore, int Kpad)
{
    __shared__ ushort lds[16384];     // 32 KB: [Ah|Al|Bh|Bl] x 4096 ushorts
    constexpr int AH0 = 0, AL0 = 4096, BH0 = 8192, BL0 = 12288;

    const int tid  = threadIdx.x;
    const int wid  = tid >> 6;        // 0..3
    const int lane = tid & 63;
    const int wm   = wid >> 1;        // 0..1
    const int wn   = wid & 1;         // 0..1
    const int l15  = lane & 15;
    const int kg   = lane >> 4;       // 0..3
    const int bm0  = blockIdx.x * 128;
    const int bn0  = blockIdx.y * 128;

    // ---- staging source pointers (inverse of LDS XOR swizzle) ----
    // load j: plane = j>>1 (0=Ah 1=Al 2=Bh 3=Bl), piece-chunk = (j&1)*256+tid
    const ushort* sP[8];
    {
        const ushort* pb[4] = {Ah, Al, Bh, Bl};
        #pragma unroll
        for (int j = 0; j < 8; ++j) {
            const int pl  = j >> 1;
            const int c   = (j & 1) * 256 + tid;
            const int pr  = c >> 3;
            const int s   = (c & 7) ^ (pr & 7);
            const int row = pr * 2 + (s >> 2);
            const int kgv = s & 3;
            const int r0  = (pl < 2) ? bm0 : bn0;
            sP[j] = pb[pl] + (size_t)(r0 + row) * Kpad + kgv * 8;
        }
    }

    f32x4 acc[4][4];
    #pragma unroll
    for (int m = 0; m < 4; ++m)
        #pragma unroll
        for (int n = 0; n < 4; ++n)
            acc[m][n] = (f32x4){0.f, 0.f, 0.f, 0.f};

    // swizzled fragment read bases (ushort units within a piece)
    const int slotA = (((lane & 1) * 4 + kg) ^ (l15 >> 1)) * 8;
    const int aswz  = wm * 2048 + (l15 >> 1) * 64 + slotA;   // + m*512
    const int bswz  = wn * 2048 + (l15 >> 1) * 64 + slotA;   // + n*512
    const int nt = Kpad >> 5;

    for (int t = 0; t < nt; ++t) {
        const int ke = t * 32;
        #pragma unroll
        for (int j = 0; j < 8; ++j)
            __builtin_amdgcn_global_load_lds(
                (const __attribute__((address_space(1))) void*)(sP[j] + ke),
                (__attribute__((address_space(3))) void*)(&lds[j * 2048 + wid * 512]),
                16, 0, 0);
        __syncthreads();              // drains vmcnt -> tile resident

        // pass order HH -> LH -> HL keeps <=3 fragment sets live
        bf16x8 aH[4], bH[4];
        #pragma unroll
        for (int m = 0; m < 4; ++m) aH[m] = *(const bf16x8*)&lds[AH0 + aswz + m * 512];
        #pragma unroll
        for (int n = 0; n < 4; ++n) bH[n] = *(const bf16x8*)&lds[BH0 + bswz + n * 512];
        __builtin_amdgcn_s_setprio(1);
        #pragma unroll
        for (int m = 0; m < 4; ++m)
            #pragma unroll
            for (int n = 0; n < 4; ++n)
                acc[m][n] = __builtin_amdgcn_mfma_f32_16x16x32_bf16(aH[m], bH[n], acc[m][n], 0, 0, 0);
        __builtin_amdgcn_s_setprio(0);
        {
            bf16x8 aL[4];
            #pragma unroll
            for (int m = 0; m < 4; ++m) aL[m] = *(const bf16x8*)&lds[AL0 + aswz + m * 512];
            __builtin_amdgcn_s_setprio(1);
            #pragma unroll
            for (int m = 0; m < 4; ++m)
                #pragma unroll
                for (int n = 0; n < 4; ++n)
                    acc[m][n] = __builtin_amdgcn_mfma_f32_16x16x32_bf16(aL[m], bH[n], acc[m][n], 0, 0, 0);
            __builtin_amdgcn_s_setprio(0);
        }
        {
            bf16x8 bL[4];
            #pragma unroll
            for (int n = 0; n < 4; ++n) bL[n] = *(const bf16x8*)&lds[BL0 + bswz + n * 512];
            __builtin_amdgcn_s_setprio(1);
            #pragma unroll
            for (int m = 0; m < 4; ++m)
                #pragma unroll
                for (int n = 0; n < 4; ++n)
                    acc[m][n] = __builtin_amdgcn_mfma_f32_16x16x32_bf16(aH[m], bL[n], acc[m][n], 0, 0, 0);
            __builtin_amdgcn_s_setprio(0);
        }
        __syncthreads();              // all reads done before next stage
    }

    // epilogue: C/D mapping col = lane&15, row = (lane>>4)*4 + reg  [m89/m91]
    #pragma unroll
    for (int n = 0; n < 4; ++n) {
        const int col = bn0 + wn * 64 + n * 16 + l15;
        if (col < Nstore) {
            const float bs = bias[col];
            #pragma unroll
            for (int m = 0; m < 4; ++m) {
                const int row = bm0 + wm * 64 + m * 16 + kg * 4;
                #pragma unroll
                for (int r = 0; r < 4; ++r)
                    C[(size_t)(row + r) * ldc + col] = acc[m][n][r] + bs;
            }
        }
    }
}

// ==================================================================
// LayerNorm + ReLU, emitting hi/lo bf16 planes (+ actions, + zero pad)
// ==================================================================
__global__ __launch_bounds__(256)
void ln_relu_split(const float* __restrict__ Y,
                   const float* __restrict__ g, const float* __restrict__ b,
                   ushort* __restrict__ Xh, ushort* __restrict__ Xl, int xstride,
                   const float* __restrict__ actions, int dopad)
{
    __shared__ float red[4];
    const int row = blockIdx.x;
    const int tid = threadIdx.x;
    const float* y = Y + (size_t)row * 1024;

    const float4 v = *(const float4*)(y + tid * 4);
    float s = v.x + v.y + v.z + v.w;
    #pragma unroll
    for (int off = 32; off > 0; off >>= 1) s += __shfl_down(s, off, 64);
    if ((tid & 63) == 0) red[tid >> 6] = s;
    __syncthreads();
    const float mu = (red[0] + red[1] + red[2] + red[3]) * (1.f / 1024.f);
    __syncthreads();
    const float d0 = v.x - mu, d1 = v.y - mu, d2 = v.z - mu, d3 = v.w - mu;
    float s2 = d0 * d0 + d1 * d1 + d2 * d2 + d3 * d3;
    #pragma unroll
    for (int off = 32; off > 0; off >>= 1) s2 += __shfl_down(s2, off, 64);
    if ((tid & 63) == 0) red[tid >> 6] = s2;
    __syncthreads();
    const float var = (red[0] + red[1] + red[2] + red[3]) * (1.f / 1024.f);
    const float inv = 1.0f / sqrtf(var + LN_EPS_F);

    float o0 = fmaxf(0.f, d0 * inv * g[tid * 4 + 0] + b[tid * 4 + 0]);
    float o1 = fmaxf(0.f, d1 * inv * g[tid * 4 + 1] + b[tid * 4 + 1]);
    float o2 = fmaxf(0.f, d2 * inv * g[tid * 4 + 2] + b[tid * 4 + 2]);
    float o3 = fmaxf(0.f, d3 * inv * g[tid * 4 + 3] + b[tid * 4 + 3]);

    ushort4 oh, ol;
    oh.x = f2bf(o0); ol.x = f2bf(o0 - bf2f(oh.x));
    oh.y = f2bf(o1); ol.y = f2bf(o1 - bf2f(oh.y));
    oh.z = f2bf(o2); ol.z = f2bf(o2 - bf2f(oh.z));
    oh.w = f2bf(o3); ol.w = f2bf(o3 - bf2f(oh.w));
    *(ushort4*)(Xh + (size_t)row * xstride + tid * 4) = oh;
    *(ushort4*)(Xl + (size_t)row * xstride + tid * 4) = ol;

    if (actions != nullptr && tid < 16) {
        const float a = actions[(size_t)row * 16 + tid];
        const ushort h = f2bf(a);
        Xh[(size_t)row * xstride + 1024 + tid] = h;
        Xl[(size_t)row * xstride + 1024 + tid] = f2bf(a - bf2f(h));
    }
    if (dopad && tid >= 16 && tid < 32) {   // zero cols 1040..1055
        Xh[(size_t)row * xstride + 1024 + tid] = 0;
        Xl[(size_t)row * xstride + 1024 + tid] = 0;
    }
}

// ---------------- fp32 matrix -> hi/lo bf16 planes, 4 elems/thread ----------
__global__ __launch_bounds__(256)
void split_mat(const float* __restrict__ src, int scols,
               ushort* __restrict__ Dh, ushort* __restrict__ Dl,
               int dcols, int total)
{
    const int idx = (blockIdx.x * 256 + threadIdx.x) * 4;
    if (idx >= total) return;
    const int r = idx / dcols, c = idx % dcols;
    float e[4];
    if (c + 3 < scols) {
        const float4 v = *(const float4*)(src + (size_t)r * scols + c);
        e[0] = v.x; e[1] = v.y; e[2] = v.z; e[3] = v.w;
    } else {
        #pragma unroll
        for (int j = 0; j < 4; ++j)
            e[j] = (c + j < scols) ? src[(size_t)r * scols + c + j] : 0.f;
    }
    ushort4 h, l;
    h.x = f2bf(e[0]); l.x = f2bf(e[0] - bf2f(h.x));
    h.y = f2bf(e[1]); l.y = f2bf(e[1] - bf2f(h.y));
    h.z = f2bf(e[2]); l.z = f2bf(e[2] - bf2f(h.z));
    h.w = f2bf(e[3]); l.w = f2bf(e[3] - bf2f(h.w));
    *(ushort4*)(Dh + idx) = h;
    *(ushort4*)(Dl + idx) = l;
}

// ---------------- concatenated head weight [wv; wa; wb; 0pad] -> planes -----
__global__ __launch_bounds__(256)
void build_wcat_split(const float* __restrict__ wv, const float* __restrict__ wa,
                      const float* __restrict__ wb, const float* __restrict__ bv,
                      const float* __restrict__ ba, const float* __restrict__ bb,
                      ushort* __restrict__ Wh, ushort* __restrict__ Wl,
                      float* __restrict__ bcat)
{
    const int idx = blockIdx.x * 256 + threadIdx.x;
    if (idx < 512 * 1024) {
        const int n = idx >> 10, k = idx & 1023;
        const float v = (n < 383) ? wv[n * 1024 + k]
                       : (n == 383) ? wa[k]
                       : (n == 384) ? wb[k] : 0.f;
        const ushort h = f2bf(v);
        Wh[idx] = h;
        Wl[idx] = f2bf(v - bf2f(h));
    }
    if (idx < 512) {
        bcat[idx] = (idx < 383) ? bv[idx] : (idx == 383) ? ba[0]
                   : (idx == 384) ? bb[0] : 0.f;
    }
}

// ==================================================================
// spline: one WAVE per row (4 rows / 256-thr block)
// ==================================================================
__device__ __forceinline__ float softplus_f(float x) {
    return (x > 20.f) ? x : log1pf(expf(x));
}

__global__ __launch_bounds__(256)
void spline_rq(const float* __restrict__ P, float* __restrict__ Out)
{
    __shared__ float cw[4][132];
    __shared__ float ch[4][132];
    __shared__ float Dv[4][132];
    const int wid  = threadIdx.x >> 6;
    const int lane = threadIdx.x & 63;
    const int r    = blockIdx.x * 4 + wid;
    const float* p = P + (size_t)r * 385;
    const int e0 = 2 * lane, e1 = 2 * lane + 1;

    const float sa = expf(p[383]);
    const float sb = p[384];

    // ---- W: softmax + affine + pair-scan -> cw[0..128] ----
    const float w0 = p[e0], w1 = p[e1];
    float mx = fmaxf(w0, w1);
    #pragma unroll
    for (int off = 1; off < 64; off <<= 1) mx = fmaxf(mx, __shfl_xor(mx, off, 64));
    const float xw0 = expf(w0 - mx), xw1 = expf(w1 - mx);
    float sw = xw0 + xw1;
    #pragma unroll
    for (int off = 1; off < 64; off <<= 1) sw += __shfl_xor(sw, off, 64);
    const float cwn = (1.f - MINW * 128.f) / sw;
    const float Wv0 = MINW + cwn * xw0;
    const float Wv1 = MINW + cwn * xw1;
    float s = Wv0 + Wv1;
    #pragma unroll
    for (int off = 1; off < 64; off <<= 1) {
        const float t = __shfl_up(s, off, 64);
        if (lane >= off) s += t;
    }
    if (lane == 0) cw[wid][0] = 0.f;
    cw[wid][e1]     = s - Wv1;
    cw[wid][e1 + 1] = (lane == 63) ? 1.0f : s;

    // ---- H: softmax + affine + pair-scan -> ch[0..128] (scaled) ----
    const float h0 = p[128 + e0], h1 = p[128 + e1];
    float mh = fmaxf(h0, h1);
    #pragma unroll
    for (int off = 1; off < 64; off <<= 1) mh = fmaxf(mh, __shfl_xor(mh, off, 64));
    const float xh0 = expf(h0 - mh), xh1 = expf(h1 - mh);
    float sh = xh0 + xh1;
    #pragma unroll
    for (int off = 1; off < 64; off <<= 1) sh += __shfl_xor(sh, off, 64);
    const float chn = (1.f - MINH * 128.f) / sh;
    const float Hv0 = MINH + chn * xh0;
    const float Hv1 = MINH + chn * xh1;
    float t2 = Hv0 + Hv1;
    #pragma unroll
    for (int off = 1; off < 64; off <<= 1) {
        const float t = __shfl_up(t2, off, 64);
        if (lane >= off) t2 += t;
    }
    if (lane == 0) ch[wid][0] = sb;
    ch[wid][e1]     = sa * (t2 - Hv1) + sb;
    ch[wid][e1 + 1] = sa * t2 + sb;

    // ---- derivatives D[0..128] ----
    if (lane == 0) { Dv[wid][0] = EDGE_CONST_F; Dv[wid][128] = EDGE_CONST_F; }
    Dv[wid][e0 + 1] = MIND + softplus_f(p[256 + e0]);
    if (lane < 63) Dv[wid][e1 + 1] = MIND + softplus_f(p[256 + e1]);

    __syncthreads();

    // ---- evaluate 2 taus per lane ----
    #pragma unroll
    for (int t = 0; t < 2; ++t) {
        const int e = 2 * lane + t;
        const float tau = ((float)e + 0.5f) * (1.f / 128.f);
        int lo = 0, hi = 128;
        #pragma unroll
        for (int it = 0; it < 7; ++it) {
            const int mid = (lo + hi) >> 1;
            if (cw[wid][mid] <= tau) lo = mid; else hi = mid;
        }
        const int bin = lo;
        const float icw = cw[wid][bin];
        const float ibw = cw[wid][bin + 1] - icw;
        const float ich = ch[wid][bin];
        const float ih  = ch[wid][bin + 1] - ich;
        const float idelta = ih / ibw;
        const float dd0 = Dv[wid][bin];
        const float dd1 = Dv[wid][bin + 1];
        const float theta = (tau - icw) / ibw;
        const float tom = theta * (1.f - theta);
        const float num = ih * (idelta * theta * theta + dd0 * tom);
        const float den = idelta + (dd0 + dd1 - 2.f * idelta) * tom;
        Out[(size_t)r * 128 + e] = ich + num / den;
    }
}

// ==================================================================
extern "C" void kernel_launch(void* const* d_in, const int* in_sizes, int n_in,
                              void* d_out, int out_size, void* d_ws, size_t ws_size,
                              hipStream_t stream) {
    const float* inputs  = (const float*)d_in[0];
    const float* actions = (const float*)d_in[1];
    const float* w1      = (const float*)d_in[2];
    const float* b1      = (const float*)d_in[3];
    const float* ln1_g   = (const float*)d_in[4];
    const float* ln1_b   = (const float*)d_in[5];
    const float* w2      = (const float*)d_in[6];
    const float* b2      = (const float*)d_in[7];
    const float* ln2_g   = (const float*)d_in[8];
    const float* ln2_b   = (const float*)d_in[9];
    const float* wv      = (const float*)d_in[10];
    const float* bv      = (const float*)d_in[11];
    const float* wa      = (const float*)d_in[12];
    const float* ba      = (const float*)d_in[13];
    const float* wb      = (const float*)d_in[14];
    const float* bb      = (const float*)d_in[15];

    // ---- workspace layout (stride 1056 for layer-2 K) ----
    float*  ws_y  = (float*)d_ws;                              // [16384][1024] f32
    ushort* ws_Xh = (ushort*)(ws_y + (size_t)16384 * 1024);    // [16384][1056] bf16 hi
    ushort* ws_Xl = ws_Xh + (size_t)16384 * 1056;              // lo plane
    ushort* w1h   = ws_Xl + (size_t)16384 * 1056;
    ushort* w1l   = w1h + 1024 * 256;
    ushort* w2h   = w1l + 1024 * 256;
    ushort* w2l   = w2h + 1024 * 1056;
    ushort* wch   = w2l + 1024 * 1056;
    ushort* wcl   = wch + 512 * 1024;
    float*  bcat  = (float*)(wcl + 512 * 1024);

    // ---- weight / input conversion to hi/lo planes ----
    split_mat<<<(16384 * 256 / 4 + 255) / 256, 256, 0, stream>>>(inputs, 256, ws_Xh, ws_Xl, 256, 16384 * 256);
    split_mat<<<(1024 * 256 / 4 + 255) / 256, 256, 0, stream>>>(w1, 256, w1h, w1l, 256, 1024 * 256);
    split_mat<<<(1024 * 1056 / 4 + 255) / 256, 256, 0, stream>>>(w2, 1040, w2h, w2l, 1056, 1024 * 1056);
    build_wcat_split<<<(512 * 1024 + 255) / 256, 256, 0, stream>>>(wv, wa, wb, bv, ba, bb, wch, wcl, bcat);

    // ---- layer 1:  [16384,256] @ [1024,256]^T ----
    gemm_bf16x3_sb<0><<<dim3(128, 8), 256, 0, stream>>>(ws_Xh, ws_Xl, w1h, w1l, b1, ws_y, 1024, 1024, 256);
    ln_relu_split<<<16384, 256, 0, stream>>>(ws_y, ln1_g, ln1_b, ws_Xh, ws_Xl, 1056, actions, 1);

    // ---- layer 2:  [16384,1056] @ [1024,1056]^T (K padded with zeros) ----
    gemm_bf16x3_sb<0><<<dim3(128, 8), 256, 0, stream>>>(ws_Xh, ws_Xl, w2h, w2l, b2, ws_y, 1024, 1024, 1056);
    ln_relu_split<<<16384, 256, 0, stream>>>(ws_y, ln2_g, ln2_b, ws_Xh, ws_Xl, 1024, nullptr, 0);

    // ---- head: [16384,1024] @ [512,1024]^T, store 385 cols ----
    gemm_bf16x3_sb<0><<<dim3(128, 4), 256, 0, stream>>>(ws_Xh, ws_Xl, wch, wcl, bcat, ws_y, 385, 385, 1024);

    // ---- spline ----
    spline_rq<<<4096, 256, 0, stream>>>(ws_y, (float*)d_out);
}